// Round 5
// baseline (3479.322 us; speedup 1.0000x reference)
//
#include <hip/hip_runtime.h>
#include <hip/hip_fp16.h>

// TGCN 2-layer, T=12, F=8, H=64, N=50k, E=800k.
// R5: (a) reuse Aglob=gconv(h0') from l1_gate as l0_gate(t+1)'s aggregation
//     (5 -> 4 row-gathers/edge/step); l0_gate's dense work fused into l1_cand.
// (b) h0/h1 fp16 mirrors packed interleaved (one 256B row per edge in the
//     dual gather). (c) 2-node interleaved gathers (16 loads in flight).

#define FT 96
#define TSTEPS 12

// ---------------- CSR build ----------------
__global__ void hist_k(const int* __restrict__ dst, int* __restrict__ deg, int E) {
    int e = blockIdx.x * blockDim.x + threadIdx.x;
    if (e < E) atomicAdd(&deg[dst[e]], 1);
}

__global__ __launch_bounds__(1024) void scan_k(int* __restrict__ deg,
                                               int* __restrict__ rowptr, int N) {
    __shared__ int sm[1024];
    __shared__ int s_carry;
    if (threadIdx.x == 0) s_carry = 0;
    __syncthreads();
    for (int base = 0; base < N; base += 1024) {
        int i = base + (int)threadIdx.x;
        int v = (i < N) ? deg[i] : 0;
        sm[threadIdx.x] = v;
        __syncthreads();
        for (int off = 1; off < 1024; off <<= 1) {
            int t = (threadIdx.x >= (unsigned)off) ? sm[threadIdx.x - off] : 0;
            __syncthreads();
            sm[threadIdx.x] += t;
            __syncthreads();
        }
        int incl = sm[threadIdx.x];
        int total = sm[1023];
        int excl = incl - v + s_carry;
        if (i < N) { rowptr[i] = excl; deg[i] = excl; }  // deg becomes cursor
        __syncthreads();
        if (threadIdx.x == 0) s_carry += total;
        __syncthreads();
    }
    if (threadIdx.x == 0) rowptr[N] = s_carry;
}

__global__ void fill_k(const int* __restrict__ src, const int* __restrict__ dst,
                       const float* __restrict__ ew, int* __restrict__ cursor,
                       int* __restrict__ csr_src, float* __restrict__ csr_w, int E) {
    int e = blockIdx.x * blockDim.x + threadIdx.x;
    if (e >= E) return;
    int pos = atomicAdd(&cursor[dst[e]], 1);
    csr_src[pos] = src[e];
    csr_w[pos] = ew[e];
}

// gather of x (fp32, one-time), writes transposed aggXt[t][n][f]
__global__ __launch_bounds__(256) void gather96_k(
    const float* __restrict__ x, const int* __restrict__ rowptr,
    const int* __restrict__ csr_src, const float* __restrict__ csr_w,
    float* __restrict__ aggXt, int N) {
    int n = blockIdx.x * 4 + (threadIdx.x >> 6);
    if (n >= N) return;
    int c = threadIdx.x & 63;
    int beg = rowptr[n], end = rowptr[n + 1];
    int deg = end - beg;
    float a0 = 0.f, a1 = 0.f;
    int sv = 0; float wv = 0.f;
    if (c < deg) { sv = csr_src[beg + c]; wv = csr_w[beg + c]; }
    int m = deg < 64 ? deg : 64;
    int m4 = (m + 3) & ~3;
#pragma unroll 4
    for (int j = 0; j < m4; ++j) {
        int s = __shfl(sv, j);
        float w = __shfl(wv, j);
        const float* row = x + (size_t)s * FT;
        a0 += w * row[c];
        if (c < 32) a1 += w * row[64 + c];
    }
    for (int e = beg + 64; e < end; ++e) {
        int s = csr_src[e]; float w = csr_w[e];
        const float* row = x + (size_t)s * FT;
        a0 += w * row[c];
        if (c < 32) a1 += w * row[64 + c];
    }
    { int f = c / 12, tt = c - f * 12;
      aggXt[((size_t)tt * N + n) * 8 + f] = a0; }
    if (c < 32) { int cc = 64 + c; int f = cc / 12, tt = cc - f * 12;
      aggXt[((size_t)tt * N + n) * 8 + f] = a1; }
}

// ---------------- gather helpers ----------------
// two nodes interleaved, fp16 feature rows (128B each): up to 16 loads in flight
__device__ __forceinline__ void gather2n_h(const __half* __restrict__ feat,
    const int* __restrict__ csr_src, const float* __restrict__ csr_w,
    int begA, int endA, int begB, int endB, int c, float& outA, float& outB) {
    int degA = endA - begA, degB = endB - begB;
    float aA = 0.f, aB = 0.f;
    int svA = 0, svB = 0; float wvA = 0.f, wvB = 0.f;
    if (c < degA) { svA = csr_src[begA + c]; wvA = csr_w[begA + c]; }
    if (c < degB) { svB = csr_src[begB + c]; wvB = csr_w[begB + c]; }
    int mA = degA < 64 ? degA : 64, mB = degB < 64 ? degB : 64;
    int m8A = (mA + 7) & ~7, m8B = (mB + 7) & ~7;
    int jmax = m8A > m8B ? m8A : m8B;
    for (int j = 0; j < jmax; j += 8) {
        if (j < m8A) {
#pragma unroll
            for (int k = 0; k < 8; ++k) {
                int s = __shfl(svA, j + k); float w = __shfl(wvA, j + k);
                aA = fmaf(w, __half2float(feat[(size_t)s * 64 + c]), aA);
            }
        }
        if (j < m8B) {
#pragma unroll
            for (int k = 0; k < 8; ++k) {
                int s = __shfl(svB, j + k); float w = __shfl(wvB, j + k);
                aB = fmaf(w, __half2float(feat[(size_t)s * 64 + c]), aB);
            }
        }
    }
    for (int e = begA + 64; e < endA; ++e)
        aA += csr_w[e] * __half2float(feat[(size_t)csr_src[e] * 64 + c]);
    for (int e = begB + 64; e < endB; ++e)
        aB += csr_w[e] * __half2float(feat[(size_t)csr_src[e] * 64 + c]);
    outA = aA; outB = aB;
}

// ---------------- t=0 standalone gate0 (dense only, Aglob = 0) -------------
__global__ __launch_bounds__(256) void g0_dense(
    const float* __restrict__ Aglob, const float* __restrict__ aggXt, int t,
    const float* __restrict__ Wg, const float* __restrict__ bg,
    const float* __restrict__ h0f, float* __restrict__ Z,
    __half* __restrict__ RH0h, int N) {
    __shared__ float sB[64 * 65];
    __shared__ float sR[64 * 65];
    __shared__ float sZ[64 * 65];
    __shared__ float sX[64 * 9];
    const int tid = threadIdx.x;
    const int lane = tid & 63;
    const int wid = __builtin_amdgcn_readfirstlane(tid >> 6);
    const int nb = blockIdx.x * 64;
    for (int i = tid; i < 4096; i += 256) {
        int nl = i >> 6, k = i & 63, n = nb + nl;
        sB[nl * 65 + k] = (n < N) ? Aglob[(size_t)n * 64 + k] : 0.f;
    }
    for (int i = tid; i < 512; i += 256) {
        int nl = i >> 3, f = i & 7, n = nb + nl;
        sX[nl * 9 + f] = (n < N) ? aggXt[((size_t)t * N + n) * 8 + f] : 0.f;
    }
    __syncthreads();
    const int col0 = wid * 32;
    float acc[32];
#pragma unroll
    for (int j = 0; j < 32; ++j) acc[j] = bg[col0 + j];
#pragma unroll
    for (int f = 0; f < 8; ++f) {
        float a = sX[lane * 9 + f];
        const float* __restrict__ w = Wg + f * 128 + col0;
#pragma unroll
        for (int j = 0; j < 32; ++j) acc[j] = fmaf(a, w[j], acc[j]);
    }
    for (int k = 0; k < 64; ++k) {
        float a = sB[lane * 65 + k];
        const float* __restrict__ w = Wg + (8 + k) * 128 + col0;
#pragma unroll
        for (int j = 0; j < 32; ++j) acc[j] = fmaf(a, w[j], acc[j]);
    }
#pragma unroll
    for (int j = 0; j < 32; ++j) acc[j] = 1.f / (1.f + __expf(-acc[j]));
    __syncthreads();
    if (col0 < 64) {
#pragma unroll
        for (int j = 0; j < 32; ++j) sR[lane * 65 + col0 + j] = acc[j];
    } else {
#pragma unroll
        for (int j = 0; j < 32; ++j) sZ[lane * 65 + (col0 - 64) + j] = acc[j];
    }
    __syncthreads();
    for (int i = tid; i < 4096; i += 256) {
        int nl = i >> 6, cc = i & 63, n = nb + nl;
        if (n < N) {
            size_t idx = (size_t)n * 64 + cc;
            RH0h[idx] = __float2half(sR[nl * 65 + cc] * h0f[idx]);
            Z[idx] = sZ[nl * 65 + cc];
        }
    }
}

// ---------------- layer-0 cand ----------------
// gather(RH0h) -> sA; c = tanh([aggX_t, sA] @ Wc0 + bc0); h0 = z*h0+(1-z)*c
__global__ __launch_bounds__(256) void l0_cand(
    const __half* __restrict__ RH0h, const float* __restrict__ aggXt, int t,
    const int* __restrict__ rowptr, const int* __restrict__ csr_src,
    const float* __restrict__ csr_w, const float* __restrict__ Wc,
    const float* __restrict__ bc, const float* __restrict__ Z,
    float* __restrict__ h0f, unsigned* __restrict__ h01, int N) {
    __shared__ float sA[64 * 65];
    __shared__ float sX[64 * 9];
    const int tid = threadIdx.x;
    const int lane = tid & 63;
    const int wid = __builtin_amdgcn_readfirstlane(tid >> 6);
    const int nb = blockIdx.x * 64;
    for (int i = 0; i < 16; i += 2) {
        int nlA = wid * 16 + i, nlB = nlA + 1;
        int nA = nb + nlA, nB = nb + nlB;
        int begA = 0, endA = 0, begB = 0, endB = 0;
        if (nA < N) { begA = rowptr[nA]; endA = rowptr[nA + 1]; }
        if (nB < N) { begB = rowptr[nB]; endB = rowptr[nB + 1]; }
        float aA, aB;
        gather2n_h(RH0h, csr_src, csr_w, begA, endA, begB, endB, lane, aA, aB);
        sA[nlA * 65 + lane] = aA;
        sA[nlB * 65 + lane] = aB;
    }
    for (int i = tid; i < 512; i += 256) {
        int nl = i >> 3, f = i & 7, n = nb + nl;
        sX[nl * 9 + f] = (n < N) ? aggXt[((size_t)t * N + n) * 8 + f] : 0.f;
    }
    __syncthreads();
    const int col0 = wid * 16;
    float acc[16];
#pragma unroll
    for (int j = 0; j < 16; ++j) acc[j] = bc[col0 + j];
#pragma unroll
    for (int f = 0; f < 8; ++f) {
        float a = sX[lane * 9 + f];
        const float* __restrict__ w = Wc + f * 64 + col0;
#pragma unroll
        for (int j = 0; j < 16; ++j) acc[j] = fmaf(a, w[j], acc[j]);
    }
    for (int k = 0; k < 64; ++k) {
        float a = sA[lane * 65 + k];
        const float* __restrict__ w = Wc + (8 + k) * 64 + col0;
#pragma unroll
        for (int j = 0; j < 16; ++j) acc[j] = fmaf(a, w[j], acc[j]);
    }
#pragma unroll
    for (int j = 0; j < 16; ++j) {
        float e = __expf(2.f * acc[j]);
        acc[j] = 1.f - 2.f / (e + 1.f);
    }
    __syncthreads();
#pragma unroll
    for (int j = 0; j < 16; ++j) sA[lane * 65 + col0 + j] = acc[j];
    __syncthreads();
    for (int i = tid; i < 4096; i += 256) {
        int nl = i >> 6, cc = i & 63, n = nb + nl;
        if (n < N) {
            size_t idx = (size_t)n * 64 + cc;
            float z = Z[idx];
            float hv = h0f[idx];
            float nh = z * hv + (1.f - z) * sA[nl * 65 + cc];
            h0f[idx] = nh;
            reinterpret_cast<__half*>(h01)[idx * 2] = __float2half(nh);
        }
    }
}

// ---------------- layer-1 gate ----------------
// dual packed gather(h01) -> sA (gconv h0'), sB (gconv h1); dump sA -> Aglob;
// rz = sigmoid([sA,sB] @ Wg1 + bg1); RH1h = r*h1, Z = z1
__global__ __launch_bounds__(256) void l1_gate(
    const unsigned* __restrict__ h01, const float* __restrict__ h1f,
    const int* __restrict__ rowptr, const int* __restrict__ csr_src,
    const float* __restrict__ csr_w, const float* __restrict__ Wg,
    const float* __restrict__ bg, float* __restrict__ Aglob,
    float* __restrict__ Z, __half* __restrict__ RH1h, int N) {
    __shared__ float sA[64 * 65];
    __shared__ float sB[64 * 65];
    const int tid = threadIdx.x;
    const int lane = tid & 63;
    const int wid = __builtin_amdgcn_readfirstlane(tid >> 6);
    const int nb = blockIdx.x * 64;
    for (int i = 0; i < 16; i += 2) {
        int nlA = wid * 16 + i, nlB = nlA + 1;
        int nA = nb + nlA, nB = nb + nlB;
        int begA = 0, endA = 0, begB = 0, endB = 0;
        if (nA < N) { begA = rowptr[nA]; endA = rowptr[nA + 1]; }
        if (nB < N) { begB = rowptr[nB]; endB = rowptr[nB + 1]; }
        int degA = endA - begA, degB = endB - begB;
        float a0A = 0.f, a1A = 0.f, a0B = 0.f, a1B = 0.f;
        int svA = 0, svB = 0; float wvA = 0.f, wvB = 0.f;
        if (lane < degA) { svA = csr_src[begA + lane]; wvA = csr_w[begA + lane]; }
        if (lane < degB) { svB = csr_src[begB + lane]; wvB = csr_w[begB + lane]; }
        int mA = degA < 64 ? degA : 64, mB = degB < 64 ? degB : 64;
        int m8A = (mA + 7) & ~7, m8B = (mB + 7) & ~7;
        int jmax = m8A > m8B ? m8A : m8B;
        for (int j = 0; j < jmax; j += 8) {
            if (j < m8A) {
#pragma unroll
                for (int k = 0; k < 8; ++k) {
                    int s = __shfl(svA, j + k); float w = __shfl(wvA, j + k);
                    unsigned v = h01[(size_t)s * 64 + lane];
                    __half2 h2 = *reinterpret_cast<const __half2*>(&v);
                    a0A = fmaf(w, __low2float(h2), a0A);
                    a1A = fmaf(w, __high2float(h2), a1A);
                }
            }
            if (j < m8B) {
#pragma unroll
                for (int k = 0; k < 8; ++k) {
                    int s = __shfl(svB, j + k); float w = __shfl(wvB, j + k);
                    unsigned v = h01[(size_t)s * 64 + lane];
                    __half2 h2 = *reinterpret_cast<const __half2*>(&v);
                    a0B = fmaf(w, __low2float(h2), a0B);
                    a1B = fmaf(w, __high2float(h2), a1B);
                }
            }
        }
        for (int e = begA + 64; e < endA; ++e) {
            float w = csr_w[e];
            unsigned v = h01[(size_t)csr_src[e] * 64 + lane];
            __half2 h2 = *reinterpret_cast<const __half2*>(&v);
            a0A = fmaf(w, __low2float(h2), a0A);
            a1A = fmaf(w, __high2float(h2), a1A);
        }
        for (int e = begB + 64; e < endB; ++e) {
            float w = csr_w[e];
            unsigned v = h01[(size_t)csr_src[e] * 64 + lane];
            __half2 h2 = *reinterpret_cast<const __half2*>(&v);
            a0B = fmaf(w, __low2float(h2), a0B);
            a1B = fmaf(w, __high2float(h2), a1B);
        }
        sA[nlA * 65 + lane] = a0A; sB[nlA * 65 + lane] = a1A;
        sA[nlB * 65 + lane] = a0B; sB[nlB * 65 + lane] = a1B;
    }
    __syncthreads();
    const int col0 = wid * 32;
    float acc[32];
#pragma unroll
    for (int j = 0; j < 32; ++j) acc[j] = bg[col0 + j];
    for (int k = 0; k < 64; ++k) {
        float a = sA[lane * 65 + k];
        const float* __restrict__ w = Wg + k * 128 + col0;
#pragma unroll
        for (int j = 0; j < 32; ++j) acc[j] = fmaf(a, w[j], acc[j]);
    }
    for (int k = 0; k < 64; ++k) {
        float a = sB[lane * 65 + k];
        const float* __restrict__ w = Wg + (64 + k) * 128 + col0;
#pragma unroll
        for (int j = 0; j < 32; ++j) acc[j] = fmaf(a, w[j], acc[j]);
    }
#pragma unroll
    for (int j = 0; j < 32; ++j) acc[j] = 1.f / (1.f + __expf(-acc[j]));
    __syncthreads();
    // dump gconv(h0') for l1_cand_fused (and next step's gate0)
    for (int i = tid; i < 4096; i += 256) {
        int nl = i >> 6, cc = i & 63, n = nb + nl;
        if (n < N) Aglob[(size_t)n * 64 + cc] = sA[nl * 65 + cc];
    }
    __syncthreads();
    if (col0 < 64) {
#pragma unroll
        for (int j = 0; j < 32; ++j) sA[lane * 65 + col0 + j] = acc[j];
    } else {
#pragma unroll
        for (int j = 0; j < 32; ++j) sB[lane * 65 + (col0 - 64) + j] = acc[j];
    }
    __syncthreads();
    for (int i = tid; i < 4096; i += 256) {
        int nl = i >> 6, cc = i & 63, n = nb + nl;
        if (n < N) {
            size_t idx = (size_t)n * 64 + cc;
            RH1h[idx] = __float2half(sA[nl * 65 + cc] * h1f[idx]);
            Z[idx] = sB[nl * 65 + cc];
        }
    }
}

// ---------------- layer-1 cand + fused gate0(t+1) ----------------
__global__ __launch_bounds__(256) void l1_cand_fused(
    const __half* __restrict__ RH1h, const float* __restrict__ Aglob,
    const float* __restrict__ aggXt, int tn, int do_gate,
    const int* __restrict__ rowptr, const int* __restrict__ csr_src,
    const float* __restrict__ csr_w, const float* __restrict__ Wc1,
    const float* __restrict__ bc1, const float* __restrict__ Wg0,
    const float* __restrict__ bg0, const float* __restrict__ h0f,
    float* __restrict__ Z, __half* __restrict__ RH0h,
    float* __restrict__ h1f, unsigned* __restrict__ h01, int N) {
    __shared__ float sA[64 * 65];   // gconv(RH1) -> then cand-c staging
    __shared__ float sB[64 * 65];   // Aglob      -> then r0 staging
    __shared__ float sZ[64 * 65];   // z0 staging
    __shared__ float sX[64 * 9];
    const int tid = threadIdx.x;
    const int lane = tid & 63;
    const int wid = __builtin_amdgcn_readfirstlane(tid >> 6);
    const int nb = blockIdx.x * 64;
    for (int i = 0; i < 16; i += 2) {
        int nlA = wid * 16 + i, nlB = nlA + 1;
        int nA = nb + nlA, nB = nb + nlB;
        int begA = 0, endA = 0, begB = 0, endB = 0;
        if (nA < N) { begA = rowptr[nA]; endA = rowptr[nA + 1]; }
        if (nB < N) { begB = rowptr[nB]; endB = rowptr[nB + 1]; }
        float aA, aB;
        gather2n_h(RH1h, csr_src, csr_w, begA, endA, begB, endB, lane, aA, aB);
        sA[nlA * 65 + lane] = aA;
        sA[nlB * 65 + lane] = aB;
    }
    for (int i = tid; i < 4096; i += 256) {
        int nl = i >> 6, k = i & 63, n = nb + nl;
        sB[nl * 65 + k] = (n < N) ? Aglob[(size_t)n * 64 + k] : 0.f;
    }
    if (do_gate) {
        for (int i = tid; i < 512; i += 256) {
            int nl = i >> 3, f = i & 7, n = nb + nl;
            sX[nl * 9 + f] = (n < N) ? aggXt[((size_t)tn * N + n) * 8 + f] : 0.f;
        }
    }
    __syncthreads();
    // B1: candidate  c = tanh([gconv(h0'), gconv(r1*h1)] @ Wc1 + bc1)
    const int col0c = wid * 16;
    float accc[16];
#pragma unroll
    for (int j = 0; j < 16; ++j) accc[j] = bc1[col0c + j];
    for (int k = 0; k < 64; ++k) {
        float a = sB[lane * 65 + k];
        const float* __restrict__ w = Wc1 + k * 64 + col0c;
#pragma unroll
        for (int j = 0; j < 16; ++j) accc[j] = fmaf(a, w[j], accc[j]);
    }
    for (int k = 0; k < 64; ++k) {
        float a = sA[lane * 65 + k];
        const float* __restrict__ w = Wc1 + (64 + k) * 64 + col0c;
#pragma unroll
        for (int j = 0; j < 16; ++j) accc[j] = fmaf(a, w[j], accc[j]);
    }
#pragma unroll
    for (int j = 0; j < 16; ++j) {
        float e = __expf(2.f * accc[j]);
        accc[j] = 1.f - 2.f / (e + 1.f);
    }
    // B2: gate0 for step tn: rz0 = sigmoid(aggX_tn @ Wg0[0:8] + Aglob @ Wg0[8:72])
    const int col0g = wid * 32;
    float accg[32];
    if (do_gate) {
#pragma unroll
        for (int j = 0; j < 32; ++j) accg[j] = bg0[col0g + j];
#pragma unroll
        for (int f = 0; f < 8; ++f) {
            float a = sX[lane * 9 + f];
            const float* __restrict__ w = Wg0 + f * 128 + col0g;
#pragma unroll
            for (int j = 0; j < 32; ++j) accg[j] = fmaf(a, w[j], accg[j]);
        }
        for (int k = 0; k < 64; ++k) {
            float a = sB[lane * 65 + k];
            const float* __restrict__ w = Wg0 + (8 + k) * 128 + col0g;
#pragma unroll
            for (int j = 0; j < 32; ++j) accg[j] = fmaf(a, w[j], accg[j]);
        }
#pragma unroll
        for (int j = 0; j < 32; ++j) accg[j] = 1.f / (1.f + __expf(-accg[j]));
    }
    __syncthreads();
    // stage: c -> sA, r0 -> sB, z0 -> sZ
#pragma unroll
    for (int j = 0; j < 16; ++j) sA[lane * 65 + col0c + j] = accc[j];
    if (do_gate) {
        if (col0g < 64) {
#pragma unroll
            for (int j = 0; j < 32; ++j) sB[lane * 65 + col0g + j] = accg[j];
        } else {
#pragma unroll
            for (int j = 0; j < 32; ++j) sZ[lane * 65 + (col0g - 64) + j] = accg[j];
        }
    }
    __syncthreads();
    for (int i = tid; i < 4096; i += 256) {
        int nl = i >> 6, cc = i & 63, n = nb + nl;
        if (n < N) {
            size_t idx = (size_t)n * 64 + cc;
            float z1 = Z[idx];
            float hv = h1f[idx];
            float nh = z1 * hv + (1.f - z1) * sA[nl * 65 + cc];
            h1f[idx] = nh;
            reinterpret_cast<__half*>(h01)[idx * 2 + 1] = __float2half(nh);
            if (do_gate) {
                RH0h[idx] = __float2half(sB[nl * 65 + cc] * h0f[idx]);
                Z[idx] = sZ[nl * 65 + cc];
            }
        }
    }
}

__global__ void out_k(const float* __restrict__ h1, const float* __restrict__ Wout,
                      const float* __restrict__ bout, float* __restrict__ out, int N) {
    int i = blockIdx.x * blockDim.x + threadIdx.x;
    int n = i >> 6;
    if (n >= N) return;
    int k = i & 63;
    float p = h1[(size_t)n * 64 + k] * Wout[k];
    for (int off = 32; off > 0; off >>= 1) p += __shfl_down(p, off);
    if (k == 0) out[n] = p + bout[0];
}

extern "C" void kernel_launch(void* const* d_in, const int* in_sizes, int n_in,
                              void* d_out, int out_size, void* d_ws, size_t ws_size,
                              hipStream_t stream) {
    const float* x   = (const float*)d_in[0];
    const int*   ei  = (const int*)d_in[1];
    const float* ew  = (const float*)d_in[2];
    const float* Wg0 = (const float*)d_in[3];
    const float* bg0 = (const float*)d_in[4];
    const float* Wc0 = (const float*)d_in[5];
    const float* bc0 = (const float*)d_in[6];
    const float* Wg1 = (const float*)d_in[7];
    const float* bg1 = (const float*)d_in[8];
    const float* Wc1 = (const float*)d_in[9];
    const float* bc1 = (const float*)d_in[10];
    const float* Wout = (const float*)d_in[11];
    const float* bout = (const float*)d_in[12];

    const int N = in_sizes[0] / FT;
    const int E = in_sizes[2];
    const int* src = ei;
    const int* dst = ei + E;

    char* p = (char*)d_ws;
    int*      deg     = (int*)p;      p += (size_t)N * 4;       // doubles as cursor
    int*      rowptr  = (int*)p;      p += (size_t)(N + 1) * 4;
    int*      csr_src = (int*)p;      p += (size_t)E * 4;
    float*    csr_w   = (float*)p;    p += (size_t)E * 4;
    float*    aggXt   = (float*)p;    p += (size_t)N * FT * 4;  // [t][n][f]
    float*    h0f     = (float*)p;    p += (size_t)N * 64 * 4;
    float*    h1f     = (float*)p;    p += (size_t)N * 64 * 4;
    float*    Aglob   = (float*)p;    p += (size_t)N * 64 * 4;
    float*    Z       = (float*)p;    p += (size_t)N * 64 * 4;
    unsigned* h01     = (unsigned*)p; p += (size_t)N * 64 * 4;  // packed fp16 (h0,h1)
    __half*   RH0h    = (__half*)p;   p += (size_t)N * 64 * 2;
    __half*   RH1h    = (__half*)p;   p += (size_t)N * 64 * 2;

    const int gE   = (E + 255) / 256;
    const int gN4  = (N + 3) / 4;
    const int gN64 = (N + 63) / 64;

    hipMemsetAsync(deg, 0, (size_t)N * 4, stream);
    hipMemsetAsync(h0f, 0, (size_t)N * 64 * 2 * 4, stream);   // h0f,h1f contiguous
    hipMemsetAsync(Aglob, 0, (size_t)N * 64 * 4, stream);
    hipMemsetAsync(h01, 0, (size_t)N * 64 * 4, stream);
    hist_k<<<gE, 256, 0, stream>>>(dst, deg, E);
    scan_k<<<1, 1024, 0, stream>>>(deg, rowptr, N);
    fill_k<<<gE, 256, 0, stream>>>(src, dst, ew, deg, csr_src, csr_w, E);
    gather96_k<<<gN4, 256, 0, stream>>>(x, rowptr, csr_src, csr_w, aggXt, N);

    // t=0 gate0 (h0=0, Aglob=0): dense only
    g0_dense<<<gN64, 256, 0, stream>>>(Aglob, aggXt, 0, Wg0, bg0, h0f, Z, RH0h, N);

    for (int t = 0; t < TSTEPS; ++t) {
        l0_cand<<<gN64, 256, 0, stream>>>(RH0h, aggXt, t, rowptr, csr_src, csr_w,
                                          Wc0, bc0, Z, h0f, h01, N);
        l1_gate<<<gN64, 256, 0, stream>>>(h01, h1f, rowptr, csr_src, csr_w,
                                          Wg1, bg1, Aglob, Z, RH1h, N);
        l1_cand_fused<<<gN64, 256, 0, stream>>>(RH1h, Aglob, aggXt, t + 1,
                                                (t + 1 < TSTEPS) ? 1 : 0,
                                                rowptr, csr_src, csr_w,
                                                Wc1, bc1, Wg0, bg0, h0f,
                                                Z, RH0h, h1f, h01, N);
    }

    out_k<<<((N * 64) + 255) / 256, 256, 0, stream>>>(h1f, Wout, bout, (float*)d_out, N);
}

// Round 6
// 2692.023 us; speedup vs baseline: 1.2925x; 1.2925x over previous
//
#include <hip/hip_runtime.h>
#include <hip/hip_fp16.h>

// TGCN 2-layer, T=12, F=8, H=64, N=50k, E=800k.
// R6: 512-thread cell kernels (2x waves/CU under same LDS) + pair-wave
// gathers (lane halves = 2 nodes, 2 channels/lane per load) -> ~2x fewer
// gather instructions at identical traffic. Algorithm unchanged from R5:
// Aglob=gconv(h0') reused as next step's gate0 aggregation (4 passes/step).

#define FT 96
#define TSTEPS 12

static __device__ __forceinline__ float lo2f(unsigned v) {
    __half2 h2 = *reinterpret_cast<const __half2*>(&v);
    return __low2float(h2);
}
static __device__ __forceinline__ float hi2f(unsigned v) {
    __half2 h2 = *reinterpret_cast<const __half2*>(&v);
    return __high2float(h2);
}

// ---------------- CSR build ----------------
__global__ void hist_k(const int* __restrict__ dst, int* __restrict__ deg, int E) {
    int e = blockIdx.x * blockDim.x + threadIdx.x;
    if (e < E) atomicAdd(&deg[dst[e]], 1);
}

__global__ __launch_bounds__(1024) void scan_k(int* __restrict__ deg,
                                               int* __restrict__ rowptr, int N) {
    __shared__ int sm[1024];
    __shared__ int s_carry;
    if (threadIdx.x == 0) s_carry = 0;
    __syncthreads();
    for (int base = 0; base < N; base += 1024) {
        int i = base + (int)threadIdx.x;
        int v = (i < N) ? deg[i] : 0;
        sm[threadIdx.x] = v;
        __syncthreads();
        for (int off = 1; off < 1024; off <<= 1) {
            int t = (threadIdx.x >= (unsigned)off) ? sm[threadIdx.x - off] : 0;
            __syncthreads();
            sm[threadIdx.x] += t;
            __syncthreads();
        }
        int incl = sm[threadIdx.x];
        int total = sm[1023];
        int excl = incl - v + s_carry;
        if (i < N) { rowptr[i] = excl; deg[i] = excl; }  // deg becomes cursor
        __syncthreads();
        if (threadIdx.x == 0) s_carry += total;
        __syncthreads();
    }
    if (threadIdx.x == 0) rowptr[N] = s_carry;
}

__global__ void fill_k(const int* __restrict__ src, const int* __restrict__ dst,
                       const float* __restrict__ ew, int* __restrict__ cursor,
                       int* __restrict__ csr_src, float* __restrict__ csr_w, int E) {
    int e = blockIdx.x * blockDim.x + threadIdx.x;
    if (e >= E) return;
    int pos = atomicAdd(&cursor[dst[e]], 1);
    csr_src[pos] = src[e];
    csr_w[pos] = ew[e];
}

// gather of x (fp32, one-time), writes transposed aggXt[t][n][f]
__global__ __launch_bounds__(256) void gather96_k(
    const float* __restrict__ x, const int* __restrict__ rowptr,
    const int* __restrict__ csr_src, const float* __restrict__ csr_w,
    float* __restrict__ aggXt, int N) {
    int n = blockIdx.x * 4 + (threadIdx.x >> 6);
    if (n >= N) return;
    int c = threadIdx.x & 63;
    int beg = rowptr[n], end = rowptr[n + 1];
    int deg = end - beg;
    float a0 = 0.f, a1 = 0.f;
    int sv = 0; float wv = 0.f;
    if (c < deg) { sv = csr_src[beg + c]; wv = csr_w[beg + c]; }
    int m = deg < 64 ? deg : 64;
    int m4 = (m + 3) & ~3;
#pragma unroll 4
    for (int j = 0; j < m4; ++j) {
        int s = __shfl(sv, j);
        float w = __shfl(wv, j);
        const float* row = x + (size_t)s * FT;
        a0 += w * row[c];
        if (c < 32) a1 += w * row[64 + c];
    }
    for (int e = beg + 64; e < end; ++e) {
        int s = csr_src[e]; float w = csr_w[e];
        const float* row = x + (size_t)s * FT;
        a0 += w * row[c];
        if (c < 32) a1 += w * row[64 + c];
    }
    { int f = c / 12, tt = c - f * 12;
      aggXt[((size_t)tt * N + n) * 8 + f] = a0; }
    if (c < 32) { int cc = 64 + c; int f = cc / 12, tt = cc - f * 12;
      aggXt[((size_t)tt * N + n) * 8 + f] = a1; }
}

// ---------------- pair-wave gather (single fp16 table, 64ch/row) ----------
// lanes 0-31: node A, lanes 32-63: node B; lane covers channels 2c2, 2c2+1.
__device__ __forceinline__ void gpair16(const unsigned* __restrict__ feat32,
    const int* __restrict__ csr_src, const float* __restrict__ csr_w,
    int begA, int degA, int begB, int degB, int lane,
    float& o0, float& o1) {
    const int half = lane >> 5, c2 = lane & 31;
    const int beg = half ? begB : begA;
    const int deg = half ? degB : degA;
    const int m = deg < 32 ? deg : 32;
    int sv = 0; float wv = 0.f;
    if (c2 < m) { sv = csr_src[beg + c2]; wv = csr_w[beg + c2]; }
    int dmax = degA > degB ? degA : degB;
    int jm = ((dmax < 32 ? dmax : 32) + 7) & ~7;
    float a0 = 0.f, a1 = 0.f;
    const int base = half << 5;
    for (int j = 0; j < jm; j += 8) {
#pragma unroll
        for (int k = 0; k < 8; ++k) {
            int s = __shfl(sv, base + j + k);
            float w = __shfl(wv, base + j + k);
            unsigned v = feat32[(size_t)s * 32 + c2];
            a0 = fmaf(w, lo2f(v), a0);
            a1 = fmaf(w, hi2f(v), a1);
        }
    }
    int end = beg + deg;
    for (int e = beg + 32; e < end; ++e) {
        float w = csr_w[e];
        unsigned v = feat32[(size_t)csr_src[e] * 32 + c2];
        a0 = fmaf(w, lo2f(v), a0);
        a1 = fmaf(w, hi2f(v), a1);
    }
    o0 = a0; o1 = a1;
}

// ---------------- t=0 standalone gate0 (dense only, Aglob = 0) -------------
__global__ __launch_bounds__(256) void g0_dense(
    const float* __restrict__ Aglob, const float* __restrict__ aggXt, int t,
    const float* __restrict__ Wg, const float* __restrict__ bg,
    const float* __restrict__ h0f, float* __restrict__ Z,
    __half* __restrict__ RH0h, int N) {
    __shared__ float sB[64 * 65];
    __shared__ float sR[64 * 65];
    __shared__ float sZ[64 * 65];
    __shared__ float sX[64 * 9];
    const int tid = threadIdx.x;
    const int lane = tid & 63;
    const int wid = __builtin_amdgcn_readfirstlane(tid >> 6);
    const int nb = blockIdx.x * 64;
    for (int i = tid; i < 4096; i += 256) {
        int nl = i >> 6, k = i & 63, n = nb + nl;
        sB[nl * 65 + k] = (n < N) ? Aglob[(size_t)n * 64 + k] : 0.f;
    }
    for (int i = tid; i < 512; i += 256) {
        int nl = i >> 3, f = i & 7, n = nb + nl;
        sX[nl * 9 + f] = (n < N) ? aggXt[((size_t)t * N + n) * 8 + f] : 0.f;
    }
    __syncthreads();
    const int col0 = wid * 32;
    float acc[32];
#pragma unroll
    for (int j = 0; j < 32; ++j) acc[j] = bg[col0 + j];
#pragma unroll
    for (int f = 0; f < 8; ++f) {
        float a = sX[lane * 9 + f];
        const float* __restrict__ w = Wg + f * 128 + col0;
#pragma unroll
        for (int j = 0; j < 32; ++j) acc[j] = fmaf(a, w[j], acc[j]);
    }
    for (int k = 0; k < 64; ++k) {
        float a = sB[lane * 65 + k];
        const float* __restrict__ w = Wg + (8 + k) * 128 + col0;
#pragma unroll
        for (int j = 0; j < 32; ++j) acc[j] = fmaf(a, w[j], acc[j]);
    }
#pragma unroll
    for (int j = 0; j < 32; ++j) acc[j] = 1.f / (1.f + __expf(-acc[j]));
    __syncthreads();
    if (col0 < 64) {
#pragma unroll
        for (int j = 0; j < 32; ++j) sR[lane * 65 + col0 + j] = acc[j];
    } else {
#pragma unroll
        for (int j = 0; j < 32; ++j) sZ[lane * 65 + (col0 - 64) + j] = acc[j];
    }
    __syncthreads();
    for (int i = tid; i < 4096; i += 256) {
        int nl = i >> 6, cc = i & 63, n = nb + nl;
        if (n < N) {
            size_t idx = (size_t)n * 64 + cc;
            RH0h[idx] = __float2half(sR[nl * 65 + cc] * h0f[idx]);
            Z[idx] = sZ[nl * 65 + cc];
        }
    }
}

// ---------------- layer-0 cand (512 thr) ----------------
__global__ __launch_bounds__(512) void l0_cand(
    const __half* __restrict__ RH0h, const float* __restrict__ aggXt, int t,
    const int* __restrict__ rowptr, const int* __restrict__ csr_src,
    const float* __restrict__ csr_w, const float* __restrict__ Wc,
    const float* __restrict__ bc, const float* __restrict__ Z,
    float* __restrict__ h0f, unsigned* __restrict__ h01, int N) {
    __shared__ float sA[64 * 65];
    __shared__ float sX[64 * 9];
    const int tid = threadIdx.x;
    const int lane = tid & 63;
    const int wid = __builtin_amdgcn_readfirstlane(tid >> 6);
    const int nb = blockIdx.x * 64;
    for (int i = 0; i < 4; ++i) {
        int pr = wid * 4 + i;
        int nlA = pr * 2, nlB = nlA + 1;
        int nA = nb + nlA, nB = nb + nlB;
        int begA = 0, degA = 0, begB = 0, degB = 0;
        if (nA < N) { begA = rowptr[nA]; degA = rowptr[nA + 1] - begA; }
        if (nB < N) { begB = rowptr[nB]; degB = rowptr[nB + 1] - begB; }
        float o0, o1;
        gpair16((const unsigned*)RH0h, csr_src, csr_w, begA, degA, begB, degB,
                lane, o0, o1);
        int nl = (lane < 32) ? nlA : nlB;
        int c2 = lane & 31;
        sA[nl * 65 + 2 * c2] = o0;
        sA[nl * 65 + 2 * c2 + 1] = o1;
    }
    { int nl = tid >> 3, f = tid & 7, n = nb + nl;
      sX[nl * 9 + f] = (n < N) ? aggXt[((size_t)t * N + n) * 8 + f] : 0.f; }
    __syncthreads();
    const int col0 = wid * 8;
    float acc[8];
#pragma unroll
    for (int j = 0; j < 8; ++j) acc[j] = bc[col0 + j];
#pragma unroll
    for (int f = 0; f < 8; ++f) {
        float a = sX[lane * 9 + f];
        const float* __restrict__ w = Wc + f * 64 + col0;
#pragma unroll
        for (int j = 0; j < 8; ++j) acc[j] = fmaf(a, w[j], acc[j]);
    }
    for (int k = 0; k < 64; ++k) {
        float a = sA[lane * 65 + k];
        const float* __restrict__ w = Wc + (8 + k) * 64 + col0;
#pragma unroll
        for (int j = 0; j < 8; ++j) acc[j] = fmaf(a, w[j], acc[j]);
    }
#pragma unroll
    for (int j = 0; j < 8; ++j) {
        float e = __expf(2.f * acc[j]);
        acc[j] = 1.f - 2.f / (e + 1.f);
    }
    __syncthreads();
#pragma unroll
    for (int j = 0; j < 8; ++j) sA[lane * 65 + col0 + j] = acc[j];
    __syncthreads();
    for (int i = tid; i < 4096; i += 512) {
        int nl = i >> 6, cc = i & 63, n = nb + nl;
        if (n < N) {
            size_t idx = (size_t)n * 64 + cc;
            float z = Z[idx];
            float hv = h0f[idx];
            float nh = z * hv + (1.f - z) * sA[nl * 65 + cc];
            h0f[idx] = nh;
            reinterpret_cast<__half*>(h01)[idx * 2] = __float2half(nh);
        }
    }
}

// ---------------- layer-1 gate (512 thr) ----------------
// pair-wave dual packed gather(h01): uint2/lane = channels (2c2,2c2+1) x (h0,h1)
__global__ __launch_bounds__(512) void l1_gate(
    const unsigned* __restrict__ h01, const float* __restrict__ h1f,
    const int* __restrict__ rowptr, const int* __restrict__ csr_src,
    const float* __restrict__ csr_w, const float* __restrict__ Wg,
    const float* __restrict__ bg, float* __restrict__ Aglob,
    float* __restrict__ Z, __half* __restrict__ RH1h, int N) {
    __shared__ float sA[64 * 65];
    __shared__ float sB[64 * 65];
    const int tid = threadIdx.x;
    const int lane = tid & 63;
    const int wid = __builtin_amdgcn_readfirstlane(tid >> 6);
    const int nb = blockIdx.x * 64;
    const uint2* __restrict__ f2 = (const uint2*)h01;
    for (int i = 0; i < 4; ++i) {
        int pr = wid * 4 + i;
        int nlA = pr * 2, nlB = nlA + 1;
        int nA = nb + nlA, nB = nb + nlB;
        int begA = 0, degA = 0, begB = 0, degB = 0;
        if (nA < N) { begA = rowptr[nA]; degA = rowptr[nA + 1] - begA; }
        if (nB < N) { begB = rowptr[nB]; degB = rowptr[nB + 1] - begB; }
        const int half = lane >> 5, c2 = lane & 31;
        const int beg = half ? begB : begA;
        const int deg = half ? degB : degA;
        const int m = deg < 32 ? deg : 32;
        int sv = 0; float wv = 0.f;
        if (c2 < m) { sv = csr_src[beg + c2]; wv = csr_w[beg + c2]; }
        int dmax = degA > degB ? degA : degB;
        int jm = ((dmax < 32 ? dmax : 32) + 7) & ~7;
        float p00 = 0.f, p01 = 0.f, p10 = 0.f, p11 = 0.f;
        const int base = half << 5;
        for (int j = 0; j < jm; j += 8) {
#pragma unroll
            for (int k = 0; k < 8; ++k) {
                int s = __shfl(sv, base + j + k);
                float w = __shfl(wv, base + j + k);
                uint2 v = f2[(size_t)s * 32 + c2];
                p00 = fmaf(w, lo2f(v.x), p00);
                p10 = fmaf(w, hi2f(v.x), p10);
                p01 = fmaf(w, lo2f(v.y), p01);
                p11 = fmaf(w, hi2f(v.y), p11);
            }
        }
        int end = beg + deg;
        for (int e = beg + 32; e < end; ++e) {
            float w = csr_w[e];
            uint2 v = f2[(size_t)csr_src[e] * 32 + c2];
            p00 = fmaf(w, lo2f(v.x), p00);
            p10 = fmaf(w, hi2f(v.x), p10);
            p01 = fmaf(w, lo2f(v.y), p01);
            p11 = fmaf(w, hi2f(v.y), p11);
        }
        int nl = (lane < 32) ? nlA : nlB;
        sA[nl * 65 + 2 * c2] = p00; sA[nl * 65 + 2 * c2 + 1] = p01;
        sB[nl * 65 + 2 * c2] = p10; sB[nl * 65 + 2 * c2 + 1] = p11;
    }
    __syncthreads();
    const int col0 = wid * 16;
    float acc[16];
#pragma unroll
    for (int j = 0; j < 16; ++j) acc[j] = bg[col0 + j];
    for (int k = 0; k < 64; ++k) {
        float a = sA[lane * 65 + k];
        const float* __restrict__ w = Wg + k * 128 + col0;
#pragma unroll
        for (int j = 0; j < 16; ++j) acc[j] = fmaf(a, w[j], acc[j]);
    }
    for (int k = 0; k < 64; ++k) {
        float a = sB[lane * 65 + k];
        const float* __restrict__ w = Wg + (64 + k) * 128 + col0;
#pragma unroll
        for (int j = 0; j < 16; ++j) acc[j] = fmaf(a, w[j], acc[j]);
    }
#pragma unroll
    for (int j = 0; j < 16; ++j) acc[j] = 1.f / (1.f + __expf(-acc[j]));
    __syncthreads();
    // dump gconv(h0') for l1_cand_fused (and next step's gate0)
    for (int i = tid; i < 4096; i += 512) {
        int nl = i >> 6, cc = i & 63, n = nb + nl;
        if (n < N) Aglob[(size_t)n * 64 + cc] = sA[nl * 65 + cc];
    }
    __syncthreads();
    if (col0 < 64) {
#pragma unroll
        for (int j = 0; j < 16; ++j) sA[lane * 65 + col0 + j] = acc[j];
    } else {
#pragma unroll
        for (int j = 0; j < 16; ++j) sB[lane * 65 + (col0 - 64) + j] = acc[j];
    }
    __syncthreads();
    for (int i = tid; i < 4096; i += 512) {
        int nl = i >> 6, cc = i & 63, n = nb + nl;
        if (n < N) {
            size_t idx = (size_t)n * 64 + cc;
            RH1h[idx] = __float2half(sA[nl * 65 + cc] * h1f[idx]);
            Z[idx] = sB[nl * 65 + cc];
        }
    }
}

// ---------------- layer-1 cand + fused gate0(t+1) (512 thr) ----------------
__global__ __launch_bounds__(512) void l1_cand_fused(
    const __half* __restrict__ RH1h, const float* __restrict__ Aglob,
    const float* __restrict__ aggXt, int tn, int do_gate,
    const int* __restrict__ rowptr, const int* __restrict__ csr_src,
    const float* __restrict__ csr_w, const float* __restrict__ Wc1,
    const float* __restrict__ bc1, const float* __restrict__ Wg0,
    const float* __restrict__ bg0, const float* __restrict__ h0f,
    float* __restrict__ Z, __half* __restrict__ RH0h,
    float* __restrict__ h1f, unsigned* __restrict__ h01, int N) {
    __shared__ float sA[64 * 65];   // gconv(RH1) -> then cand-c staging
    __shared__ float sB[64 * 65];   // Aglob      -> then r0 staging
    __shared__ float sZ[64 * 65];   // z0 staging
    __shared__ float sX[64 * 9];
    const int tid = threadIdx.x;
    const int lane = tid & 63;
    const int wid = __builtin_amdgcn_readfirstlane(tid >> 6);
    const int nb = blockIdx.x * 64;
    for (int i = 0; i < 4; ++i) {
        int pr = wid * 4 + i;
        int nlA = pr * 2, nlB = nlA + 1;
        int nA = nb + nlA, nB = nb + nlB;
        int begA = 0, degA = 0, begB = 0, degB = 0;
        if (nA < N) { begA = rowptr[nA]; degA = rowptr[nA + 1] - begA; }
        if (nB < N) { begB = rowptr[nB]; degB = rowptr[nB + 1] - begB; }
        float o0, o1;
        gpair16((const unsigned*)RH1h, csr_src, csr_w, begA, degA, begB, degB,
                lane, o0, o1);
        int nl = (lane < 32) ? nlA : nlB;
        int c2 = lane & 31;
        sA[nl * 65 + 2 * c2] = o0;
        sA[nl * 65 + 2 * c2 + 1] = o1;
    }
    for (int i = tid; i < 4096; i += 512) {
        int nl = i >> 6, k = i & 63, n = nb + nl;
        sB[nl * 65 + k] = (n < N) ? Aglob[(size_t)n * 64 + k] : 0.f;
    }
    if (do_gate) {
        int nl = tid >> 3, f = tid & 7, n = nb + nl;
        sX[nl * 9 + f] = (n < N) ? aggXt[((size_t)tn * N + n) * 8 + f] : 0.f;
    }
    __syncthreads();
    // cand: c = tanh([gconv(h0'), gconv(r1*h1)] @ Wc1 + bc1)
    const int col0c = wid * 8;
    float accc[8];
#pragma unroll
    for (int j = 0; j < 8; ++j) accc[j] = bc1[col0c + j];
    for (int k = 0; k < 64; ++k) {
        float a = sB[lane * 65 + k];
        const float* __restrict__ w = Wc1 + k * 64 + col0c;
#pragma unroll
        for (int j = 0; j < 8; ++j) accc[j] = fmaf(a, w[j], accc[j]);
    }
    for (int k = 0; k < 64; ++k) {
        float a = sA[lane * 65 + k];
        const float* __restrict__ w = Wc1 + (64 + k) * 64 + col0c;
#pragma unroll
        for (int j = 0; j < 8; ++j) accc[j] = fmaf(a, w[j], accc[j]);
    }
#pragma unroll
    for (int j = 0; j < 8; ++j) {
        float e = __expf(2.f * accc[j]);
        accc[j] = 1.f - 2.f / (e + 1.f);
    }
    // gate0 for step tn: rz0 = sigmoid(aggX_tn @ Wg0[0:8] + Aglob @ Wg0[8:72])
    const int col0g = wid * 16;
    float accg[16];
    if (do_gate) {
#pragma unroll
        for (int j = 0; j < 16; ++j) accg[j] = bg0[col0g + j];
#pragma unroll
        for (int f = 0; f < 8; ++f) {
            float a = sX[lane * 9 + f];
            const float* __restrict__ w = Wg0 + f * 128 + col0g;
#pragma unroll
            for (int j = 0; j < 16; ++j) accg[j] = fmaf(a, w[j], accg[j]);
        }
        for (int k = 0; k < 64; ++k) {
            float a = sB[lane * 65 + k];
            const float* __restrict__ w = Wg0 + (8 + k) * 128 + col0g;
#pragma unroll
            for (int j = 0; j < 16; ++j) accg[j] = fmaf(a, w[j], accg[j]);
        }
#pragma unroll
        for (int j = 0; j < 16; ++j) accg[j] = 1.f / (1.f + __expf(-accg[j]));
    }
    __syncthreads();
    // stage: c -> sA, r0 -> sB, z0 -> sZ
#pragma unroll
    for (int j = 0; j < 8; ++j) sA[lane * 65 + col0c + j] = accc[j];
    if (do_gate) {
        if (col0g < 64) {
#pragma unroll
            for (int j = 0; j < 16; ++j) sB[lane * 65 + col0g + j] = accg[j];
        } else {
#pragma unroll
            for (int j = 0; j < 16; ++j) sZ[lane * 65 + (col0g - 64) + j] = accg[j];
        }
    }
    __syncthreads();
    for (int i = tid; i < 4096; i += 512) {
        int nl = i >> 6, cc = i & 63, n = nb + nl;
        if (n < N) {
            size_t idx = (size_t)n * 64 + cc;
            float z1 = Z[idx];
            float hv = h1f[idx];
            float nh = z1 * hv + (1.f - z1) * sA[nl * 65 + cc];
            h1f[idx] = nh;
            reinterpret_cast<__half*>(h01)[idx * 2 + 1] = __float2half(nh);
            if (do_gate) {
                RH0h[idx] = __float2half(sB[nl * 65 + cc] * h0f[idx]);
                Z[idx] = sZ[nl * 65 + cc];
            }
        }
    }
}

__global__ void out_k(const float* __restrict__ h1, const float* __restrict__ Wout,
                      const float* __restrict__ bout, float* __restrict__ out, int N) {
    int i = blockIdx.x * blockDim.x + threadIdx.x;
    int n = i >> 6;
    if (n >= N) return;
    int k = i & 63;
    float p = h1[(size_t)n * 64 + k] * Wout[k];
    for (int off = 32; off > 0; off >>= 1) p += __shfl_down(p, off);
    if (k == 0) out[n] = p + bout[0];
}

static inline size_t align16(size_t v) { return (v + 15) & ~(size_t)15; }

extern "C" void kernel_launch(void* const* d_in, const int* in_sizes, int n_in,
                              void* d_out, int out_size, void* d_ws, size_t ws_size,
                              hipStream_t stream) {
    const float* x   = (const float*)d_in[0];
    const int*   ei  = (const int*)d_in[1];
    const float* ew  = (const float*)d_in[2];
    const float* Wg0 = (const float*)d_in[3];
    const float* bg0 = (const float*)d_in[4];
    const float* Wc0 = (const float*)d_in[5];
    const float* bc0 = (const float*)d_in[6];
    const float* Wg1 = (const float*)d_in[7];
    const float* bg1 = (const float*)d_in[8];
    const float* Wc1 = (const float*)d_in[9];
    const float* bc1 = (const float*)d_in[10];
    const float* Wout = (const float*)d_in[11];
    const float* bout = (const float*)d_in[12];

    const int N = in_sizes[0] / FT;
    const int E = in_sizes[2];
    const int* src = ei;
    const int* dst = ei + E;

    char* base = (char*)d_ws;
    size_t off = 0;
    int* deg = (int*)(base + off);          off = align16(off + (size_t)N * 4);
    int* rowptr = (int*)(base + off);       off = align16(off + (size_t)(N + 1) * 4);
    int* csr_src = (int*)(base + off);      off = align16(off + (size_t)E * 4);
    float* csr_w = (float*)(base + off);    off = align16(off + (size_t)E * 4);
    float* aggXt = (float*)(base + off);    off = align16(off + (size_t)N * FT * 4);
    float* h0f = (float*)(base + off);      off = align16(off + (size_t)N * 64 * 4);
    float* h1f = (float*)(base + off);      off = align16(off + (size_t)N * 64 * 4);
    float* Aglob = (float*)(base + off);    off = align16(off + (size_t)N * 64 * 4);
    float* Z = (float*)(base + off);        off = align16(off + (size_t)N * 64 * 4);
    unsigned* h01 = (unsigned*)(base + off); off = align16(off + (size_t)N * 64 * 4);
    __half* RH0h = (__half*)(base + off);   off = align16(off + (size_t)N * 64 * 2);
    __half* RH1h = (__half*)(base + off);   off = align16(off + (size_t)N * 64 * 2);

    const int gE   = (E + 255) / 256;
    const int gN4  = (N + 3) / 4;
    const int gN64 = (N + 63) / 64;

    hipMemsetAsync(deg, 0, (size_t)N * 4, stream);
    hipMemsetAsync(h0f, 0, (size_t)N * 64 * 4, stream);
    hipMemsetAsync(h1f, 0, (size_t)N * 64 * 4, stream);
    hipMemsetAsync(Aglob, 0, (size_t)N * 64 * 4, stream);
    hipMemsetAsync(h01, 0, (size_t)N * 64 * 4, stream);
    hist_k<<<gE, 256, 0, stream>>>(dst, deg, E);
    scan_k<<<1, 1024, 0, stream>>>(deg, rowptr, N);
    fill_k<<<gE, 256, 0, stream>>>(src, dst, ew, deg, csr_src, csr_w, E);
    gather96_k<<<gN4, 256, 0, stream>>>(x, rowptr, csr_src, csr_w, aggXt, N);

    // t=0 gate0 (h0=0, Aglob=0): dense only
    g0_dense<<<gN64, 256, 0, stream>>>(Aglob, aggXt, 0, Wg0, bg0, h0f, Z, RH0h, N);

    for (int t = 0; t < TSTEPS; ++t) {
        l0_cand<<<gN64, 512, 0, stream>>>(RH0h, aggXt, t, rowptr, csr_src, csr_w,
                                          Wc0, bc0, Z, h0f, h01, N);
        l1_gate<<<gN64, 512, 0, stream>>>(h01, h1f, rowptr, csr_src, csr_w,
                                          Wg1, bg1, Aglob, Z, RH1h, N);
        l1_cand_fused<<<gN64, 512, 0, stream>>>(RH1h, Aglob, aggXt, t + 1,
                                                (t + 1 < TSTEPS) ? 1 : 0,
                                                rowptr, csr_src, csr_w,
                                                Wc1, bc1, Wg0, bg0, h0f,
                                                Z, RH0h, h1f, h01, N);
    }

    out_k<<<((N * 64) + 255) / 256, 256, 0, stream>>>(h1f, Wout, bout, (float*)d_out, N);
}

// Round 7
// 2563.250 us; speedup vs baseline: 1.3574x; 1.0502x over previous
//
#include <hip/hip_runtime.h>
#include <hip/hip_fp16.h>

// TGCN 2-layer, T=12, F=8, H=64, N=50k, E=800k.
// R7: (1) multi-block CSR scan (kills 90us serial scan_k);
// (2) packed edge record ew32 = src(16b)|fp16(w)<<16 -> 1 shfl/edge, half csr
//     bytes; 16 loads in flight in single-table gathers;
// (3) l1_cand_fused LDS 52->35.5KB via two-phase epilogue (4 blocks/CU);
// (4) x pre-cast to fp16 for the one-time gather96.

#define FT 96
#define TSTEPS 12

static __device__ __forceinline__ float lo2f(unsigned v) {
    __half2 h2 = *reinterpret_cast<const __half2*>(&v);
    return __low2float(h2);
}
static __device__ __forceinline__ float hi2f(unsigned v) {
    __half2 h2 = *reinterpret_cast<const __half2*>(&v);
    return __high2float(h2);
}
static __device__ __forceinline__ float wof(unsigned p) {
    return __half2float(__ushort_as_half((unsigned short)(p >> 16)));
}

// ---------------- CSR build ----------------
__global__ void hist_k(const int* __restrict__ dst, int* __restrict__ deg, int E) {
    int e = blockIdx.x * blockDim.x + threadIdx.x;
    if (e < E) atomicAdd(&deg[dst[e]], 1);
}

// per-256-chunk sums
__global__ __launch_bounds__(256) void partial_k(const int* __restrict__ deg,
                                                 int* __restrict__ part, int N) {
    __shared__ int sm[256];
    int i = blockIdx.x * 256 + threadIdx.x;
    sm[threadIdx.x] = (i < N) ? deg[i] : 0;
    __syncthreads();
    for (int off = 128; off > 0; off >>= 1) {
        if (threadIdx.x < off) sm[threadIdx.x] += sm[threadIdx.x + off];
        __syncthreads();
    }
    if (threadIdx.x == 0) part[blockIdx.x] = sm[0];
}

// exclusive scan of G<=256 partials; writes rowptr[N]=total
__global__ __launch_bounds__(256) void scanpart_k(int* __restrict__ part,
                                                  int* __restrict__ rowptr,
                                                  int G, int N) {
    __shared__ int sm[256];
    int v = (threadIdx.x < G) ? part[threadIdx.x] : 0;
    sm[threadIdx.x] = v;
    __syncthreads();
    for (int off = 1; off < 256; off <<= 1) {
        int t = (threadIdx.x >= (unsigned)off) ? sm[threadIdx.x - off] : 0;
        __syncthreads();
        sm[threadIdx.x] += t;
        __syncthreads();
    }
    if (threadIdx.x < G) part[threadIdx.x] = sm[threadIdx.x] - v;  // exclusive
    if (threadIdx.x == 255) rowptr[N] = sm[255];
}

// per-chunk exclusive scan + global offset -> rowptr, cursor
__global__ __launch_bounds__(256) void scanchunk_k(const int* __restrict__ deg,
                                                   const int* __restrict__ part,
                                                   int* __restrict__ rowptr,
                                                   int* __restrict__ cursor, int N) {
    __shared__ int sm[256];
    int i = blockIdx.x * 256 + threadIdx.x;
    int v = (i < N) ? deg[i] : 0;
    sm[threadIdx.x] = v;
    __syncthreads();
    for (int off = 1; off < 256; off <<= 1) {
        int t = (threadIdx.x >= (unsigned)off) ? sm[threadIdx.x - off] : 0;
        __syncthreads();
        sm[threadIdx.x] += t;
        __syncthreads();
    }
    int excl = sm[threadIdx.x] - v + part[blockIdx.x];
    if (i < N) { rowptr[i] = excl; cursor[i] = excl; }
}

// fill packed records: low16 = src (N<65536), high16 = fp16 weight bits
__global__ void fill_k(const int* __restrict__ src, const int* __restrict__ dst,
                       const float* __restrict__ ew, int* __restrict__ cursor,
                       unsigned* __restrict__ csr_ew, int E) {
    int e = blockIdx.x * blockDim.x + threadIdx.x;
    if (e >= E) return;
    int pos = atomicAdd(&cursor[dst[e]], 1);
    unsigned hw = (unsigned)__half_as_ushort(__float2half(ew[e]));
    csr_ew[pos] = (unsigned)src[e] | (hw << 16);
}

// x -> fp16 cast
__global__ void x2h_k(const float* __restrict__ x, __half* __restrict__ xh, int M) {
    int i = blockIdx.x * blockDim.x + threadIdx.x;
    if (i < M) xh[i] = __float2half(x[i]);
}

// gather of xh (96 fp16 ch/node), writes transposed aggXt[t][n][f]
__global__ __launch_bounds__(256) void gather96_k(
    const __half* __restrict__ xh, const int* __restrict__ rowptr,
    const unsigned* __restrict__ csr_ew, float* __restrict__ aggXt, int N) {
    int n = blockIdx.x * 4 + (threadIdx.x >> 6);
    if (n >= N) return;
    int c = threadIdx.x & 63;
    int beg = rowptr[n], end = rowptr[n + 1];
    int deg = end - beg;
    float a0 = 0.f, a1 = 0.f;
    unsigned ev = 0;
    if (c < deg) ev = csr_ew[beg + c];
    int m = deg < 64 ? deg : 64;
    int m8 = (m + 7) & ~7;
#pragma unroll 8
    for (int j = 0; j < m8; ++j) {
        unsigned p = __shfl(ev, j);
        int s = p & 0xffff;
        float w = wof(p);
        const __half* row = xh + (size_t)s * FT;
        a0 = fmaf(w, __half2float(row[c]), a0);
        if (c < 32) a1 = fmaf(w, __half2float(row[64 + c]), a1);
    }
    for (int e = beg + 64; e < end; ++e) {
        unsigned p = csr_ew[e];
        int s = p & 0xffff;
        float w = wof(p);
        const __half* row = xh + (size_t)s * FT;
        a0 = fmaf(w, __half2float(row[c]), a0);
        if (c < 32) a1 = fmaf(w, __half2float(row[64 + c]), a1);
    }
    { int f = c / 12, tt = c - f * 12;
      aggXt[((size_t)tt * N + n) * 8 + f] = a0; }
    if (c < 32) { int cc = 64 + c; int f = cc / 12, tt = cc - f * 12;
      aggXt[((size_t)tt * N + n) * 8 + f] = a1; }
}

// ---------------- pair-wave gather (single fp16 table, 64ch/row) ----------
// lanes 0-31: node A, lanes 32-63: node B; lane covers channels 2c2, 2c2+1.
__device__ __forceinline__ void gpair16(const unsigned* __restrict__ feat32,
    const unsigned* __restrict__ csr_ew,
    int begA, int degA, int begB, int degB, int lane,
    float& o0, float& o1) {
    const int half = lane >> 5, c2 = lane & 31;
    const int beg = half ? begB : begA;
    const int deg = half ? degB : degA;
    const int m = deg < 32 ? deg : 32;
    unsigned ev = 0;
    if (c2 < m) ev = csr_ew[beg + c2];   // others: src=0, w=+0 -> no-op
    int dmax = degA > degB ? degA : degB;
    int jm = dmax < 32 ? dmax : 32;
    jm = (jm + 15) & ~15;
    float a0 = 0.f, a1 = 0.f;
    const int base = half << 5;
    for (int j = 0; j < jm; j += 16) {
        unsigned vv[16]; float ww[16];
#pragma unroll
        for (int k = 0; k < 16; ++k) {
            unsigned p = __shfl(ev, base + j + k);
            ww[k] = wof(p);
            vv[k] = feat32[(size_t)(p & 0xffff) * 32 + c2];
        }
#pragma unroll
        for (int k = 0; k < 16; ++k) {
            a0 = fmaf(ww[k], lo2f(vv[k]), a0);
            a1 = fmaf(ww[k], hi2f(vv[k]), a1);
        }
    }
    int end = beg + deg;
    for (int e = beg + 32; e < end; ++e) {
        unsigned p = csr_ew[e];
        float w = wof(p);
        unsigned v = feat32[(size_t)(p & 0xffff) * 32 + c2];
        a0 = fmaf(w, lo2f(v), a0);
        a1 = fmaf(w, hi2f(v), a1);
    }
    o0 = a0; o1 = a1;
}

// ---------------- t=0 standalone gate0 (dense only, Aglob = 0) -------------
__global__ __launch_bounds__(256) void g0_dense(
    const float* __restrict__ Aglob, const float* __restrict__ aggXt, int t,
    const float* __restrict__ Wg, const float* __restrict__ bg,
    const float* __restrict__ h0f, float* __restrict__ Z,
    __half* __restrict__ RH0h, int N) {
    __shared__ float sB[64 * 65];
    __shared__ float sR[64 * 65];
    __shared__ float sZ[64 * 65];
    __shared__ float sX[64 * 9];
    const int tid = threadIdx.x;
    const int lane = tid & 63;
    const int wid = __builtin_amdgcn_readfirstlane(tid >> 6);
    const int nb = blockIdx.x * 64;
    for (int i = tid; i < 4096; i += 256) {
        int nl = i >> 6, k = i & 63, n = nb + nl;
        sB[nl * 65 + k] = (n < N) ? Aglob[(size_t)n * 64 + k] : 0.f;
    }
    for (int i = tid; i < 512; i += 256) {
        int nl = i >> 3, f = i & 7, n = nb + nl;
        sX[nl * 9 + f] = (n < N) ? aggXt[((size_t)t * N + n) * 8 + f] : 0.f;
    }
    __syncthreads();
    const int col0 = wid * 32;
    float acc[32];
#pragma unroll
    for (int j = 0; j < 32; ++j) acc[j] = bg[col0 + j];
#pragma unroll
    for (int f = 0; f < 8; ++f) {
        float a = sX[lane * 9 + f];
        const float* __restrict__ w = Wg + f * 128 + col0;
#pragma unroll
        for (int j = 0; j < 32; ++j) acc[j] = fmaf(a, w[j], acc[j]);
    }
    for (int k = 0; k < 64; ++k) {
        float a = sB[lane * 65 + k];
        const float* __restrict__ w = Wg + (8 + k) * 128 + col0;
#pragma unroll
        for (int j = 0; j < 32; ++j) acc[j] = fmaf(a, w[j], acc[j]);
    }
#pragma unroll
    for (int j = 0; j < 32; ++j) acc[j] = 1.f / (1.f + __expf(-acc[j]));
    __syncthreads();
    if (col0 < 64) {
#pragma unroll
        for (int j = 0; j < 32; ++j) sR[lane * 65 + col0 + j] = acc[j];
    } else {
#pragma unroll
        for (int j = 0; j < 32; ++j) sZ[lane * 65 + (col0 - 64) + j] = acc[j];
    }
    __syncthreads();
    for (int i = tid; i < 4096; i += 256) {
        int nl = i >> 6, cc = i & 63, n = nb + nl;
        if (n < N) {
            size_t idx = (size_t)n * 64 + cc;
            RH0h[idx] = __float2half(sR[nl * 65 + cc] * h0f[idx]);
            Z[idx] = sZ[nl * 65 + cc];
        }
    }
}

// ---------------- layer-0 cand (512 thr) ----------------
__global__ __launch_bounds__(512) void l0_cand(
    const __half* __restrict__ RH0h, const float* __restrict__ aggXt, int t,
    const int* __restrict__ rowptr, const unsigned* __restrict__ csr_ew,
    const float* __restrict__ Wc, const float* __restrict__ bc,
    const float* __restrict__ Z, float* __restrict__ h0f,
    unsigned* __restrict__ h01, int N) {
    __shared__ float sA[64 * 65];
    __shared__ float sX[64 * 9];
    const int tid = threadIdx.x;
    const int lane = tid & 63;
    const int wid = __builtin_amdgcn_readfirstlane(tid >> 6);
    const int nb = blockIdx.x * 64;
    for (int i = 0; i < 4; ++i) {
        int pr = wid * 4 + i;
        int nlA = pr * 2, nlB = nlA + 1;
        int nA = nb + nlA, nB = nb + nlB;
        int begA = 0, degA = 0, begB = 0, degB = 0;
        if (nA < N) { begA = rowptr[nA]; degA = rowptr[nA + 1] - begA; }
        if (nB < N) { begB = rowptr[nB]; degB = rowptr[nB + 1] - begB; }
        float o0, o1;
        gpair16((const unsigned*)RH0h, csr_ew, begA, degA, begB, degB, lane, o0, o1);
        int nl = (lane < 32) ? nlA : nlB;
        int c2 = lane & 31;
        sA[nl * 65 + 2 * c2] = o0;
        sA[nl * 65 + 2 * c2 + 1] = o1;
    }
    { int nl = tid >> 3, f = tid & 7, n = nb + nl;
      sX[nl * 9 + f] = (n < N) ? aggXt[((size_t)t * N + n) * 8 + f] : 0.f; }
    __syncthreads();
    const int col0 = wid * 8;
    float acc[8];
#pragma unroll
    for (int j = 0; j < 8; ++j) acc[j] = bc[col0 + j];
#pragma unroll
    for (int f = 0; f < 8; ++f) {
        float a = sX[lane * 9 + f];
        const float* __restrict__ w = Wc + f * 64 + col0;
#pragma unroll
        for (int j = 0; j < 8; ++j) acc[j] = fmaf(a, w[j], acc[j]);
    }
    for (int k = 0; k < 64; ++k) {
        float a = sA[lane * 65 + k];
        const float* __restrict__ w = Wc + (8 + k) * 64 + col0;
#pragma unroll
        for (int j = 0; j < 8; ++j) acc[j] = fmaf(a, w[j], acc[j]);
    }
#pragma unroll
    for (int j = 0; j < 8; ++j) {
        float e = __expf(2.f * acc[j]);
        acc[j] = 1.f - 2.f / (e + 1.f);
    }
    __syncthreads();
#pragma unroll
    for (int j = 0; j < 8; ++j) sA[lane * 65 + col0 + j] = acc[j];
    __syncthreads();
    for (int i = tid; i < 4096; i += 512) {
        int nl = i >> 6, cc = i & 63, n = nb + nl;
        if (n < N) {
            size_t idx = (size_t)n * 64 + cc;
            float z = Z[idx];
            float hv = h0f[idx];
            float nh = z * hv + (1.f - z) * sA[nl * 65 + cc];
            h0f[idx] = nh;
            reinterpret_cast<__half*>(h01)[idx * 2] = __float2half(nh);
        }
    }
}

// ---------------- layer-1 gate (512 thr) ----------------
__global__ __launch_bounds__(512) void l1_gate(
    const unsigned* __restrict__ h01, const float* __restrict__ h1f,
    const int* __restrict__ rowptr, const unsigned* __restrict__ csr_ew,
    const float* __restrict__ Wg, const float* __restrict__ bg,
    float* __restrict__ Aglob, float* __restrict__ Z,
    __half* __restrict__ RH1h, int N) {
    __shared__ float sA[64 * 65];
    __shared__ float sB[64 * 65];
    const int tid = threadIdx.x;
    const int lane = tid & 63;
    const int wid = __builtin_amdgcn_readfirstlane(tid >> 6);
    const int nb = blockIdx.x * 64;
    const uint2* __restrict__ f2 = (const uint2*)h01;
    for (int i = 0; i < 4; ++i) {
        int pr = wid * 4 + i;
        int nlA = pr * 2, nlB = nlA + 1;
        int nA = nb + nlA, nB = nb + nlB;
        int begA = 0, degA = 0, begB = 0, degB = 0;
        if (nA < N) { begA = rowptr[nA]; degA = rowptr[nA + 1] - begA; }
        if (nB < N) { begB = rowptr[nB]; degB = rowptr[nB + 1] - begB; }
        const int half = lane >> 5, c2 = lane & 31;
        const int beg = half ? begB : begA;
        const int deg = half ? degB : degA;
        const int m = deg < 32 ? deg : 32;
        unsigned ev = 0;
        if (c2 < m) ev = csr_ew[beg + c2];
        int dmax = degA > degB ? degA : degB;
        int jm = dmax < 32 ? dmax : 32;
        jm = (jm + 7) & ~7;
        float p00 = 0.f, p01 = 0.f, p10 = 0.f, p11 = 0.f;
        const int base = half << 5;
        for (int j = 0; j < jm; j += 8) {
            uint2 vv[8]; float ww[8];
#pragma unroll
            for (int k = 0; k < 8; ++k) {
                unsigned p = __shfl(ev, base + j + k);
                ww[k] = wof(p);
                vv[k] = f2[(size_t)(p & 0xffff) * 32 + c2];
            }
#pragma unroll
            for (int k = 0; k < 8; ++k) {
                p00 = fmaf(ww[k], lo2f(vv[k].x), p00);
                p10 = fmaf(ww[k], hi2f(vv[k].x), p10);
                p01 = fmaf(ww[k], lo2f(vv[k].y), p01);
                p11 = fmaf(ww[k], hi2f(vv[k].y), p11);
            }
        }
        int end = beg + deg;
        for (int e = beg + 32; e < end; ++e) {
            unsigned p = csr_ew[e];
            float w = wof(p);
            uint2 v = f2[(size_t)(p & 0xffff) * 32 + c2];
            p00 = fmaf(w, lo2f(v.x), p00);
            p10 = fmaf(w, hi2f(v.x), p10);
            p01 = fmaf(w, lo2f(v.y), p01);
            p11 = fmaf(w, hi2f(v.y), p11);
        }
        int nl = (lane < 32) ? nlA : nlB;
        int c2w = lane & 31;
        sA[nl * 65 + 2 * c2w] = p00; sA[nl * 65 + 2 * c2w + 1] = p01;
        sB[nl * 65 + 2 * c2w] = p10; sB[nl * 65 + 2 * c2w + 1] = p11;
    }
    __syncthreads();
    const int col0 = wid * 16;
    float acc[16];
#pragma unroll
    for (int j = 0; j < 16; ++j) acc[j] = bg[col0 + j];
    for (int k = 0; k < 64; ++k) {
        float a = sA[lane * 65 + k];
        const float* __restrict__ w = Wg + k * 128 + col0;
#pragma unroll
        for (int j = 0; j < 16; ++j) acc[j] = fmaf(a, w[j], acc[j]);
    }
    for (int k = 0; k < 64; ++k) {
        float a = sB[lane * 65 + k];
        const float* __restrict__ w = Wg + (64 + k) * 128 + col0;
#pragma unroll
        for (int j = 0; j < 16; ++j) acc[j] = fmaf(a, w[j], acc[j]);
    }
#pragma unroll
    for (int j = 0; j < 16; ++j) acc[j] = 1.f / (1.f + __expf(-acc[j]));
    __syncthreads();
    // dump gconv(h0') for l1_cand_fused (and next step's gate0)
    for (int i = tid; i < 4096; i += 512) {
        int nl = i >> 6, cc = i & 63, n = nb + nl;
        if (n < N) Aglob[(size_t)n * 64 + cc] = sA[nl * 65 + cc];
    }
    __syncthreads();
    if (col0 < 64) {
#pragma unroll
        for (int j = 0; j < 16; ++j) sA[lane * 65 + col0 + j] = acc[j];
    } else {
#pragma unroll
        for (int j = 0; j < 16; ++j) sB[lane * 65 + (col0 - 64) + j] = acc[j];
    }
    __syncthreads();
    for (int i = tid; i < 4096; i += 512) {
        int nl = i >> 6, cc = i & 63, n = nb + nl;
        if (n < N) {
            size_t idx = (size_t)n * 64 + cc;
            RH1h[idx] = __float2half(sA[nl * 65 + cc] * h1f[idx]);
            Z[idx] = sB[nl * 65 + cc];
        }
    }
}

// ---------------- layer-1 cand + fused gate0(t+1) (512 thr) ----------------
// LDS: sA + sB + sX = 35.5 KB -> 4 blocks/CU. Two-phase epilogue replaces sZ.
__global__ __launch_bounds__(512) void l1_cand_fused(
    const __half* __restrict__ RH1h, const float* __restrict__ Aglob,
    const float* __restrict__ aggXt, int tn, int do_gate,
    const int* __restrict__ rowptr, const unsigned* __restrict__ csr_ew,
    const float* __restrict__ Wc1, const float* __restrict__ bc1,
    const float* __restrict__ Wg0, const float* __restrict__ bg0,
    const float* __restrict__ h0f, float* __restrict__ Z,
    __half* __restrict__ RH0h, float* __restrict__ h1f,
    unsigned* __restrict__ h01, int N) {
    __shared__ float sA[64 * 65];   // gconv(RH1) -> cand-c staging
    __shared__ float sB[64 * 65];   // Aglob -> r0 staging -> z0 staging
    __shared__ float sX[64 * 9];
    const int tid = threadIdx.x;
    const int lane = tid & 63;
    const int wid = __builtin_amdgcn_readfirstlane(tid >> 6);
    const int nb = blockIdx.x * 64;
    for (int i = 0; i < 4; ++i) {
        int pr = wid * 4 + i;
        int nlA = pr * 2, nlB = nlA + 1;
        int nA = nb + nlA, nB = nb + nlB;
        int begA = 0, degA = 0, begB = 0, degB = 0;
        if (nA < N) { begA = rowptr[nA]; degA = rowptr[nA + 1] - begA; }
        if (nB < N) { begB = rowptr[nB]; degB = rowptr[nB + 1] - begB; }
        float o0, o1;
        gpair16((const unsigned*)RH1h, csr_ew, begA, degA, begB, degB, lane, o0, o1);
        int nl = (lane < 32) ? nlA : nlB;
        int c2 = lane & 31;
        sA[nl * 65 + 2 * c2] = o0;
        sA[nl * 65 + 2 * c2 + 1] = o1;
    }
    for (int i = tid; i < 4096; i += 512) {
        int nl = i >> 6, k = i & 63, n = nb + nl;
        sB[nl * 65 + k] = (n < N) ? Aglob[(size_t)n * 64 + k] : 0.f;
    }
    if (do_gate) {
        int nl = tid >> 3, f = tid & 7, n = nb + nl;
        sX[nl * 9 + f] = (n < N) ? aggXt[((size_t)tn * N + n) * 8 + f] : 0.f;
    }
    __syncthreads();
    // cand: c = tanh([gconv(h0'), gconv(r1*h1)] @ Wc1 + bc1)
    const int col0c = wid * 8;
    float accc[8];
#pragma unroll
    for (int j = 0; j < 8; ++j) accc[j] = bc1[col0c + j];
    for (int k = 0; k < 64; ++k) {
        float a = sB[lane * 65 + k];
        const float* __restrict__ w = Wc1 + k * 64 + col0c;
#pragma unroll
        for (int j = 0; j < 8; ++j) accc[j] = fmaf(a, w[j], accc[j]);
    }
    for (int k = 0; k < 64; ++k) {
        float a = sA[lane * 65 + k];
        const float* __restrict__ w = Wc1 + (64 + k) * 64 + col0c;
#pragma unroll
        for (int j = 0; j < 8; ++j) accc[j] = fmaf(a, w[j], accc[j]);
    }
#pragma unroll
    for (int j = 0; j < 8; ++j) {
        float e = __expf(2.f * accc[j]);
        accc[j] = 1.f - 2.f / (e + 1.f);
    }
    // gate0 for step tn: rz0 = sigmoid(aggX_tn @ Wg0[0:8] + Aglob @ Wg0[8:72])
    const int col0g = wid * 16;
    float accg[16];
    if (do_gate) {
#pragma unroll
        for (int j = 0; j < 16; ++j) accg[j] = bg0[col0g + j];
#pragma unroll
        for (int f = 0; f < 8; ++f) {
            float a = sX[lane * 9 + f];
            const float* __restrict__ w = Wg0 + f * 128 + col0g;
#pragma unroll
            for (int j = 0; j < 16; ++j) accg[j] = fmaf(a, w[j], accg[j]);
        }
        for (int k = 0; k < 64; ++k) {
            float a = sB[lane * 65 + k];
            const float* __restrict__ w = Wg0 + (8 + k) * 128 + col0g;
#pragma unroll
            for (int j = 0; j < 16; ++j) accg[j] = fmaf(a, w[j], accg[j]);
        }
#pragma unroll
        for (int j = 0; j < 16; ++j) accg[j] = 1.f / (1.f + __expf(-accg[j]));
    }
    __syncthreads();
    // phase-1 staging: c -> sA, r0 (cols<64) -> sB
#pragma unroll
    for (int j = 0; j < 8; ++j) sA[lane * 65 + col0c + j] = accc[j];
    if (do_gate && col0g < 64) {
#pragma unroll
        for (int j = 0; j < 16; ++j) sB[lane * 65 + col0g + j] = accg[j];
    }
    __syncthreads();
    // epilogue-1: h1 update (reads z1 from Z) + RH0h (uses r0 in sB)
    for (int i = tid; i < 4096; i += 512) {
        int nl = i >> 6, cc = i & 63, n = nb + nl;
        if (n < N) {
            size_t idx = (size_t)n * 64 + cc;
            float z1 = Z[idx];
            float hv = h1f[idx];
            float nh = z1 * hv + (1.f - z1) * sA[nl * 65 + cc];
            h1f[idx] = nh;
            reinterpret_cast<__half*>(h01)[idx * 2 + 1] = __float2half(nh);
            if (do_gate) RH0h[idx] = __float2half(sB[nl * 65 + cc] * h0f[idx]);
        }
    }
    if (do_gate) {
        __syncthreads();
        // phase-2 staging: z0 -> sB
        if (col0g >= 64) {
#pragma unroll
            for (int j = 0; j < 16; ++j) sB[lane * 65 + (col0g - 64) + j] = accg[j];
        }
        __syncthreads();
        for (int i = tid; i < 4096; i += 512) {
            int nl = i >> 6, cc = i & 63, n = nb + nl;
            if (n < N) Z[(size_t)n * 64 + cc] = sB[nl * 65 + cc];
        }
    }
}

__global__ void out_k(const float* __restrict__ h1, const float* __restrict__ Wout,
                      const float* __restrict__ bout, float* __restrict__ out, int N) {
    int i = blockIdx.x * blockDim.x + threadIdx.x;
    int n = i >> 6;
    if (n >= N) return;
    int k = i & 63;
    float p = h1[(size_t)n * 64 + k] * Wout[k];
    for (int off = 32; off > 0; off >>= 1) p += __shfl_down(p, off);
    if (k == 0) out[n] = p + bout[0];
}

static inline size_t align16(size_t v) { return (v + 15) & ~(size_t)15; }

extern "C" void kernel_launch(void* const* d_in, const int* in_sizes, int n_in,
                              void* d_out, int out_size, void* d_ws, size_t ws_size,
                              hipStream_t stream) {
    const float* x   = (const float*)d_in[0];
    const int*   ei  = (const int*)d_in[1];
    const float* ew  = (const float*)d_in[2];
    const float* Wg0 = (const float*)d_in[3];
    const float* bg0 = (const float*)d_in[4];
    const float* Wc0 = (const float*)d_in[5];
    const float* bc0 = (const float*)d_in[6];
    const float* Wg1 = (const float*)d_in[7];
    const float* bg1 = (const float*)d_in[8];
    const float* Wc1 = (const float*)d_in[9];
    const float* bc1 = (const float*)d_in[10];
    const float* Wout = (const float*)d_in[11];
    const float* bout = (const float*)d_in[12];

    const int N = in_sizes[0] / FT;
    const int E = in_sizes[2];
    const int* src = ei;
    const int* dst = ei + E;

    char* base = (char*)d_ws;
    size_t off = 0;
    int* deg = (int*)(base + off);           off = align16(off + (size_t)N * 4);
    int* cursor = (int*)(base + off);        off = align16(off + (size_t)N * 4);
    int* rowptr = (int*)(base + off);        off = align16(off + (size_t)(N + 1) * 4);
    int* part = (int*)(base + off);          off = align16(off + 256 * 4);
    unsigned* csr_ew = (unsigned*)(base + off); off = align16(off + (size_t)E * 4);
    float* aggXt = (float*)(base + off);     off = align16(off + (size_t)N * FT * 4);
    float* h0f = (float*)(base + off);       off = align16(off + (size_t)N * 64 * 4);
    float* h1f = (float*)(base + off);       off = align16(off + (size_t)N * 64 * 4);
    float* Aglob = (float*)(base + off);     off = align16(off + (size_t)N * 64 * 4);
    float* Z = (float*)(base + off);         off = align16(off + (size_t)N * 64 * 4);
    unsigned* h01 = (unsigned*)(base + off); off = align16(off + (size_t)N * 64 * 4);
    __half* RH0h = (__half*)(base + off);    off = align16(off + (size_t)N * 64 * 2);
    __half* RH1h = (__half*)(base + off);    off = align16(off + (size_t)N * 64 * 2);
    __half* xh = (__half*)(base + off);      off = align16(off + (size_t)N * FT * 2);

    const int gE   = (E + 255) / 256;
    const int gN4  = (N + 3) / 4;
    const int gN64 = (N + 63) / 64;
    const int G    = (N + 255) / 256;       // scan chunks (196 <= 256)

    hipMemsetAsync(deg, 0, (size_t)N * 4, stream);
    hipMemsetAsync(h0f, 0, (size_t)N * 64 * 4, stream);
    hipMemsetAsync(h1f, 0, (size_t)N * 64 * 4, stream);
    hipMemsetAsync(Aglob, 0, (size_t)N * 64 * 4, stream);
    hipMemsetAsync(h01, 0, (size_t)N * 64 * 4, stream);

    x2h_k<<<(N * FT + 255) / 256, 256, 0, stream>>>(x, xh, N * FT);
    hist_k<<<gE, 256, 0, stream>>>(dst, deg, E);
    partial_k<<<G, 256, 0, stream>>>(deg, part, N);
    scanpart_k<<<1, 256, 0, stream>>>(part, rowptr, G, N);
    scanchunk_k<<<G, 256, 0, stream>>>(deg, part, rowptr, cursor, N);
    fill_k<<<gE, 256, 0, stream>>>(src, dst, ew, cursor, csr_ew, E);
    gather96_k<<<gN4, 256, 0, stream>>>(xh, rowptr, csr_ew, aggXt, N);

    // t=0 gate0 (h0=0, Aglob=0): dense only
    g0_dense<<<gN64, 256, 0, stream>>>(Aglob, aggXt, 0, Wg0, bg0, h0f, Z, RH0h, N);

    for (int t = 0; t < TSTEPS; ++t) {
        l0_cand<<<gN64, 512, 0, stream>>>(RH0h, aggXt, t, rowptr, csr_ew,
                                          Wc0, bc0, Z, h0f, h01, N);
        l1_gate<<<gN64, 512, 0, stream>>>(h01, h1f, rowptr, csr_ew,
                                          Wg1, bg1, Aglob, Z, RH1h, N);
        l1_cand_fused<<<gN64, 512, 0, stream>>>(RH1h, Aglob, aggXt, t + 1,
                                                (t + 1 < TSTEPS) ? 1 : 0,
                                                rowptr, csr_ew,
                                                Wc1, bc1, Wg0, bg0, h0f,
                                                Z, RH0h, h1f, h01, N);
    }

    out_k<<<((N * 64) + 255) / 256, 256, 0, stream>>>(h1f, Wout, bout, (float*)d_out, N);
}

// Round 8
// 1964.847 us; speedup vs baseline: 1.7708x; 1.3046x over previous
//
#include <hip/hip_runtime.h>
#include <hip/hip_fp16.h>

// TGCN 2-layer, T=12, F=8, H=64, N=50k, E=800k.
// R8: dense phases via v_mfma_f32_16x16x32_f16 (agg tiles fp16 in LDS,
// weights pre-transposed fp16 [C][K], bias pre-loaded into acc).
// Z and Aglob demoted to fp16 (traffic halved). out_k folded into the final
// l1_cand_fused. Gather structure (packed edges, pair-wave) from R7.

#define FT 96
#define TSTEPS 12

typedef _Float16 f16x8 __attribute__((ext_vector_type(8)));
typedef float f32x4 __attribute__((ext_vector_type(4)));

static __device__ __forceinline__ float lo2f(unsigned v) {
    __half2 h2 = *reinterpret_cast<const __half2*>(&v);
    return __low2float(h2);
}
static __device__ __forceinline__ float hi2f(unsigned v) {
    __half2 h2 = *reinterpret_cast<const __half2*>(&v);
    return __high2float(h2);
}
static __device__ __forceinline__ float wof(unsigned p) {
    return __half2float(__ushort_as_half((unsigned short)(p >> 16)));
}

// ---------------- CSR build ----------------
__global__ void hist_k(const int* __restrict__ dst, int* __restrict__ deg, int E) {
    int e = blockIdx.x * blockDim.x + threadIdx.x;
    if (e < E) atomicAdd(&deg[dst[e]], 1);
}

__global__ __launch_bounds__(256) void partial_k(const int* __restrict__ deg,
                                                 int* __restrict__ part, int N) {
    __shared__ int sm[256];
    int i = blockIdx.x * 256 + threadIdx.x;
    sm[threadIdx.x] = (i < N) ? deg[i] : 0;
    __syncthreads();
    for (int off = 128; off > 0; off >>= 1) {
        if (threadIdx.x < off) sm[threadIdx.x] += sm[threadIdx.x + off];
        __syncthreads();
    }
    if (threadIdx.x == 0) part[blockIdx.x] = sm[0];
}

__global__ __launch_bounds__(256) void scanpart_k(int* __restrict__ part,
                                                  int* __restrict__ rowptr,
                                                  int G, int N) {
    __shared__ int sm[256];
    int v = (threadIdx.x < G) ? part[threadIdx.x] : 0;
    sm[threadIdx.x] = v;
    __syncthreads();
    for (int off = 1; off < 256; off <<= 1) {
        int t = (threadIdx.x >= (unsigned)off) ? sm[threadIdx.x - off] : 0;
        __syncthreads();
        sm[threadIdx.x] += t;
        __syncthreads();
    }
    if (threadIdx.x < G) part[threadIdx.x] = sm[threadIdx.x] - v;
    if (threadIdx.x == 255) rowptr[N] = sm[255];
}

__global__ __launch_bounds__(256) void scanchunk_k(const int* __restrict__ deg,
                                                   const int* __restrict__ part,
                                                   int* __restrict__ rowptr,
                                                   int* __restrict__ cursor, int N) {
    __shared__ int sm[256];
    int i = blockIdx.x * 256 + threadIdx.x;
    int v = (i < N) ? deg[i] : 0;
    sm[threadIdx.x] = v;
    __syncthreads();
    for (int off = 1; off < 256; off <<= 1) {
        int t = (threadIdx.x >= (unsigned)off) ? sm[threadIdx.x - off] : 0;
        __syncthreads();
        sm[threadIdx.x] += t;
        __syncthreads();
    }
    int excl = sm[threadIdx.x] - v + part[blockIdx.x];
    if (i < N) { rowptr[i] = excl; cursor[i] = excl; }
}

__global__ void fill_k(const int* __restrict__ src, const int* __restrict__ dst,
                       const float* __restrict__ ew, int* __restrict__ cursor,
                       unsigned* __restrict__ csr_ew, int E) {
    int e = blockIdx.x * blockDim.x + threadIdx.x;
    if (e >= E) return;
    int pos = atomicAdd(&cursor[dst[e]], 1);
    unsigned hw = (unsigned)__half_as_ushort(__float2half(ew[e]));
    csr_ew[pos] = (unsigned)src[e] | (hw << 16);
}

__global__ void x2h_k(const float* __restrict__ x, _Float16* __restrict__ xh, int M) {
    int i = blockIdx.x * blockDim.x + threadIdx.x;
    if (i < M) xh[i] = (_Float16)x[i];
}

// weight prep: fp16 transposed [C][K] layouts
__global__ void wprep_k(const float* __restrict__ Wg0, const float* __restrict__ Wc0,
                        const float* __restrict__ Wg1, const float* __restrict__ Wc1,
                        _Float16* __restrict__ Wg1t, _Float16* __restrict__ Wc1t,
                        _Float16* __restrict__ Wc0t, _Float16* __restrict__ Wg0t_h,
                        _Float16* __restrict__ Wg0t_x) {
    int i = blockIdx.x * 256 + threadIdx.x;
    if (i < 128 * 128) { int c = i >> 7, k = i & 127; Wg1t[i] = (_Float16)Wg1[k * 128 + c]; }
    if (i < 64 * 128)  { int c = i >> 7, k = i & 127; Wc1t[i] = (_Float16)Wc1[k * 64 + c]; }
    if (i < 64 * 96)   { int c = i / 96, k = i - c * 96;
                         Wc0t[i] = (k < 72) ? (_Float16)Wc0[k * 64 + c] : (_Float16)0.f; }
    if (i < 128 * 64)  { int c = i >> 6, k = i & 63; Wg0t_h[i] = (_Float16)Wg0[(8 + k) * 128 + c]; }
    if (i < 128 * 32)  { int c = i >> 5, k = i & 31;
                         Wg0t_x[i] = (k < 8) ? (_Float16)Wg0[k * 128 + c] : (_Float16)0.f; }
}

// gather of xh (96 fp16 ch/node), writes transposed aggXt[t][n][f]
__global__ __launch_bounds__(256) void gather96_k(
    const _Float16* __restrict__ xh, const int* __restrict__ rowptr,
    const unsigned* __restrict__ csr_ew, float* __restrict__ aggXt, int N) {
    int n = blockIdx.x * 4 + (threadIdx.x >> 6);
    if (n >= N) return;
    int c = threadIdx.x & 63;
    int beg = rowptr[n], end = rowptr[n + 1];
    int deg = end - beg;
    float a0 = 0.f, a1 = 0.f;
    unsigned ev = 0;
    if (c < deg) ev = csr_ew[beg + c];
    int m = deg < 64 ? deg : 64;
    int m8 = (m + 7) & ~7;
#pragma unroll 8
    for (int j = 0; j < m8; ++j) {
        unsigned p = __shfl(ev, j);
        int s = p & 0xffff;
        float w = wof(p);
        const _Float16* row = xh + (size_t)s * FT;
        a0 = fmaf(w, (float)row[c], a0);
        if (c < 32) a1 = fmaf(w, (float)row[64 + c], a1);
    }
    for (int e = beg + 64; e < end; ++e) {
        unsigned p = csr_ew[e];
        int s = p & 0xffff;
        float w = wof(p);
        const _Float16* row = xh + (size_t)s * FT;
        a0 = fmaf(w, (float)row[c], a0);
        if (c < 32) a1 = fmaf(w, (float)row[64 + c], a1);
    }
    { int f = c / 12, tt = c - f * 12;
      aggXt[((size_t)tt * N + n) * 8 + f] = a0; }
    if (c < 32) { int cc = 64 + c; int f = cc / 12, tt = cc - f * 12;
      aggXt[((size_t)tt * N + n) * 8 + f] = a1; }
}

// t=0 gate0 (h0=0): only z0 needed (r0*h0 = 0)
__global__ void g0z_k(const float* __restrict__ aggXt, const float* __restrict__ Wg0,
                      const float* __restrict__ bg0, _Float16* __restrict__ Zh, int N) {
    int i = blockIdx.x * blockDim.x + threadIdx.x;
    int n = i >> 6;
    if (n >= N) return;
    int c = i & 63;
    float acc = bg0[64 + c];
#pragma unroll
    for (int f = 0; f < 8; ++f) acc += aggXt[(size_t)n * 8 + f] * Wg0[f * 128 + 64 + c];
    Zh[(size_t)n * 64 + c] = (_Float16)(1.f / (1.f + __expf(-acc)));
}

// pair-wave gather: lanes 0-31 node A, 32-63 node B; lane = channels 2c2,2c2+1
__device__ __forceinline__ void gpair16(const unsigned* __restrict__ feat32,
    const unsigned* __restrict__ csr_ew,
    int begA, int degA, int begB, int degB, int lane,
    float& o0, float& o1) {
    const int half = lane >> 5, c2 = lane & 31;
    const int beg = half ? begB : begA;
    const int deg = half ? degB : degA;
    const int m = deg < 32 ? deg : 32;
    unsigned ev = 0;
    if (c2 < m) ev = csr_ew[beg + c2];
    int dmax = degA > degB ? degA : degB;
    int jm = dmax < 32 ? dmax : 32;
    jm = (jm + 15) & ~15;
    float a0 = 0.f, a1 = 0.f;
    const int base = half << 5;
    for (int j = 0; j < jm; j += 16) {
        unsigned vv[16]; float ww[16];
#pragma unroll
        for (int k = 0; k < 16; ++k) {
            unsigned p = __shfl(ev, base + j + k);
            ww[k] = wof(p);
            vv[k] = feat32[(size_t)(p & 0xffff) * 32 + c2];
        }
#pragma unroll
        for (int k = 0; k < 16; ++k) {
            a0 = fmaf(ww[k], lo2f(vv[k]), a0);
            a1 = fmaf(ww[k], hi2f(vv[k]), a1);
        }
    }
    int end = beg + deg;
    for (int e = beg + 32; e < end; ++e) {
        unsigned p = csr_ew[e];
        float w = wof(p);
        unsigned v = feat32[(size_t)(p & 0xffff) * 32 + c2];
        a0 = fmaf(w, lo2f(v), a0);
        a1 = fmaf(w, hi2f(v), a1);
    }
    o0 = a0; o1 = a1;
}

// ---------------- layer-0 cand (512 thr, MFMA dense) ----------------
// A-tile sA[64][104] fp16: k0-7 aggX, k8-71 gconv(RH0), k72-95 zero.
__global__ __launch_bounds__(512) void l0_cand(
    const _Float16* __restrict__ RH0h, const float* __restrict__ aggXt, int t,
    const int* __restrict__ rowptr, const unsigned* __restrict__ csr_ew,
    const _Float16* __restrict__ Wc0t, const float* __restrict__ bc,
    const _Float16* __restrict__ Zh, float* __restrict__ h0f,
    unsigned* __restrict__ h01, int N) {
    __shared__ _Float16 sA[64 * 104];
    const int tid = threadIdx.x;
    const int lane = tid & 63;
    const int wid = __builtin_amdgcn_readfirstlane(tid >> 6);
    const int nb = blockIdx.x * 64;
    // zero pad cols 72..103
    { int nl = tid >> 3, k0 = 72 + ((tid & 7) << 2);
#pragma unroll
      for (int q = 0; q < 4; ++q) sA[nl * 104 + k0 + q] = (_Float16)0.f; }
    // aggX fill cols 0..7
    { int nl = tid >> 3, f = tid & 7, n = nb + nl;
      sA[nl * 104 + f] = (n < N) ? (_Float16)aggXt[((size_t)t * N + n) * 8 + f] : (_Float16)0.f; }
    // gather cols 8..71
    for (int i = 0; i < 4; ++i) {
        int pr = wid * 4 + i;
        int nlA = pr * 2, nlB = nlA + 1;
        int nA = nb + nlA, nB = nb + nlB;
        int begA = 0, degA = 0, begB = 0, degB = 0;
        if (nA < N) { begA = rowptr[nA]; degA = rowptr[nA + 1] - begA; }
        if (nB < N) { begB = rowptr[nB]; degB = rowptr[nB + 1] - begB; }
        float o0, o1;
        gpair16((const unsigned*)RH0h, csr_ew, begA, degA, begB, degB, lane, o0, o1);
        int nl = (lane < 32) ? nlA : nlB;
        int c2 = lane & 31;
        sA[nl * 104 + 8 + 2 * c2] = (_Float16)o0;
        sA[nl * 104 + 8 + 2 * c2 + 1] = (_Float16)o1;
    }
    __syncthreads();
    // dense: out[64][64] = sA @ Wc0t^T (K=96), tanh
    const int ln15 = lane & 15, quad = lane >> 4;
    const int mt = wid & 3, ng = wid >> 2;       // ng 0..1, 2 N-tiles each
    const int mrow = mt * 16 + ln15;
    f16x8 afr[3];
#pragma unroll
    for (int kc = 0; kc < 3; ++kc)
        afr[kc] = *(const f16x8*)&sA[mrow * 104 + kc * 32 + quad * 8];
    f32x4 acc[2];
    int cols[2];
#pragma unroll
    for (int nt = 0; nt < 2; ++nt) {
        int col = (ng * 2 + nt) * 16 + ln15;
        cols[nt] = col;
        float b = bc[col];
        f32x4 a = {b, b, b, b};
#pragma unroll
        for (int kc = 0; kc < 3; ++kc) {
            f16x8 bfr = *(const f16x8*)&Wc0t[(size_t)col * 96 + kc * 32 + quad * 8];
            a = __builtin_amdgcn_mfma_f32_16x16x32_f16(afr[kc], bfr, a, 0, 0, 0);
        }
        acc[nt] = a;
    }
    __syncthreads();
    // stage c into sA cols 0..63
#pragma unroll
    for (int nt = 0; nt < 2; ++nt) {
#pragma unroll
        for (int r = 0; r < 4; ++r) {
            float e = __expf(2.f * acc[nt][r]);
            float c = 1.f - 2.f / (e + 1.f);
            int row = mt * 16 + quad * 4 + r;
            sA[row * 104 + cols[nt]] = (_Float16)c;
        }
    }
    __syncthreads();
    for (int i = tid; i < 4096; i += 512) {
        int nl = i >> 6, cc = i & 63, n = nb + nl;
        if (n < N) {
            size_t idx = (size_t)n * 64 + cc;
            float z = (float)Zh[idx];
            float hv = h0f[idx];
            float nh = z * hv + (1.f - z) * (float)sA[nl * 104 + cc];
            h0f[idx] = nh;
            reinterpret_cast<__half*>(h01)[idx * 2] = __float2half(nh);
        }
    }
}

// ---------------- layer-1 gate (512 thr, MFMA dense) ----------------
// A-tile sA[64][136]: k0-63 gconv(h0'), k64-127 gconv(h1)
__global__ __launch_bounds__(512) void l1_gate(
    const unsigned* __restrict__ h01, const float* __restrict__ h1f,
    const int* __restrict__ rowptr, const unsigned* __restrict__ csr_ew,
    const _Float16* __restrict__ Wg1t, const float* __restrict__ bg,
    unsigned* __restrict__ Aglobh32, _Float16* __restrict__ Zh,
    _Float16* __restrict__ RH1h, int N) {
    __shared__ _Float16 sA[64 * 136];
    const int tid = threadIdx.x;
    const int lane = tid & 63;
    const int wid = __builtin_amdgcn_readfirstlane(tid >> 6);
    const int nb = blockIdx.x * 64;
    const uint2* __restrict__ f2 = (const uint2*)h01;
    for (int i = 0; i < 4; ++i) {
        int pr = wid * 4 + i;
        int nlA = pr * 2, nlB = nlA + 1;
        int nA = nb + nlA, nB = nb + nlB;
        int begA = 0, degA = 0, begB = 0, degB = 0;
        if (nA < N) { begA = rowptr[nA]; degA = rowptr[nA + 1] - begA; }
        if (nB < N) { begB = rowptr[nB]; degB = rowptr[nB + 1] - begB; }
        const int half = lane >> 5, c2 = lane & 31;
        const int beg = half ? begB : begA;
        const int deg = half ? degB : degA;
        const int m = deg < 32 ? deg : 32;
        unsigned ev = 0;
        if (c2 < m) ev = csr_ew[beg + c2];
        int dmax = degA > degB ? degA : degB;
        int jm = dmax < 32 ? dmax : 32;
        jm = (jm + 7) & ~7;
        float p00 = 0.f, p01 = 0.f, p10 = 0.f, p11 = 0.f;
        const int base = half << 5;
        for (int j = 0; j < jm; j += 8) {
            uint2 vv[8]; float ww[8];
#pragma unroll
            for (int k = 0; k < 8; ++k) {
                unsigned p = __shfl(ev, base + j + k);
                ww[k] = wof(p);
                vv[k] = f2[(size_t)(p & 0xffff) * 32 + c2];
            }
#pragma unroll
            for (int k = 0; k < 8; ++k) {
                p00 = fmaf(ww[k], lo2f(vv[k].x), p00);
                p10 = fmaf(ww[k], hi2f(vv[k].x), p10);
                p01 = fmaf(ww[k], lo2f(vv[k].y), p01);
                p11 = fmaf(ww[k], hi2f(vv[k].y), p11);
            }
        }
        int end = beg + deg;
        for (int e = beg + 32; e < end; ++e) {
            unsigned p = csr_ew[e];
            float w = wof(p);
            uint2 v = f2[(size_t)(p & 0xffff) * 32 + c2];
            p00 = fmaf(w, lo2f(v.x), p00);
            p10 = fmaf(w, hi2f(v.x), p10);
            p01 = fmaf(w, lo2f(v.y), p01);
            p11 = fmaf(w, hi2f(v.y), p11);
        }
        int nl = (lane < 32) ? nlA : nlB;
        int c2w = lane & 31;
        sA[nl * 136 + 2 * c2w] = (_Float16)p00;
        sA[nl * 136 + 2 * c2w + 1] = (_Float16)p01;
        sA[nl * 136 + 64 + 2 * c2w] = (_Float16)p10;
        sA[nl * 136 + 64 + 2 * c2w + 1] = (_Float16)p11;
    }
    __syncthreads();
    // Aglob dump (fp16, packed u32 view) — reads sA cols 0..63
    for (int i = tid; i < 2048; i += 512) {
        int nl = i >> 5, c2 = i & 31, n = nb + nl;
        if (n < N) Aglobh32[(size_t)n * 32 + c2] = ((const unsigned*)sA)[nl * 68 + c2];
    }
    // dense: rz[64][128] = sA @ Wg1t^T (K=128), sigmoid
    const int ln15 = lane & 15, quad = lane >> 4;
    const int mt = wid & 3, ng = wid >> 2;       // ng 0..1, 4 N-tiles each
    const int mrow = mt * 16 + ln15;
    f16x8 afr[4];
#pragma unroll
    for (int kc = 0; kc < 4; ++kc)
        afr[kc] = *(const f16x8*)&sA[mrow * 136 + kc * 32 + quad * 8];
    f32x4 acc[4];
    int cols[4];
#pragma unroll
    for (int nt = 0; nt < 4; ++nt) {
        int col = (ng * 4 + nt) * 16 + ln15;
        cols[nt] = col;
        float b = bg[col];
        f32x4 a = {b, b, b, b};
#pragma unroll
        for (int kc = 0; kc < 4; ++kc) {
            f16x8 bfr = *(const f16x8*)&Wg1t[(size_t)col * 128 + kc * 32 + quad * 8];
            a = __builtin_amdgcn_mfma_f32_16x16x32_f16(afr[kc], bfr, a, 0, 0, 0);
        }
        acc[nt] = a;
    }
    __syncthreads();
    // stage r (cols 0-63) and z (cols 64-127) into sA
#pragma unroll
    for (int nt = 0; nt < 4; ++nt) {
#pragma unroll
        for (int r = 0; r < 4; ++r) {
            float s = 1.f / (1.f + __expf(-acc[nt][r]));
            int row = mt * 16 + quad * 4 + r;
            sA[row * 136 + cols[nt]] = (_Float16)s;
        }
    }
    __syncthreads();
    for (int i = tid; i < 4096; i += 512) {
        int nl = i >> 6, cc = i & 63, n = nb + nl;
        if (n < N) {
            size_t idx = (size_t)n * 64 + cc;
            float r = (float)sA[nl * 136 + cc];
            float z = (float)sA[nl * 136 + 64 + cc];
            RH1h[idx] = (_Float16)(r * h1f[idx]);
            Zh[idx] = (_Float16)z;
        }
    }
}

// ---------------- layer-1 cand + fused gate0(t+1) (512 thr, MFMA) ----------
// sA[64][136]: k0-63 = Aglobh (gconv h0'), k64-127 = gconv(RH1).
// sX32[64][40]: k0-7 aggX(t+1), rest 0.
__global__ __launch_bounds__(512) void l1_cand_fused(
    const _Float16* __restrict__ RH1h, const unsigned* __restrict__ Aglobh32,
    const float* __restrict__ aggXt, int tn, int do_gate, int final,
    const int* __restrict__ rowptr, const unsigned* __restrict__ csr_ew,
    const _Float16* __restrict__ Wc1t, const float* __restrict__ bc1,
    const _Float16* __restrict__ Wg0t_h, const _Float16* __restrict__ Wg0t_x,
    const float* __restrict__ bg0, const float* __restrict__ h0f,
    _Float16* __restrict__ Zh, _Float16* __restrict__ RH0h,
    float* __restrict__ h1f, unsigned* __restrict__ h01,
    const float* __restrict__ Wout, const float* __restrict__ bout,
    float* __restrict__ out, int N) {
    __shared__ _Float16 sA[64 * 136];
    __shared__ _Float16 sX[64 * 40];
    const int tid = threadIdx.x;
    const int lane = tid & 63;
    const int wid = __builtin_amdgcn_readfirstlane(tid >> 6);
    const int nb = blockIdx.x * 64;
    // sX zero (cols 8..39) + aggX fill (cols 0..7)
    { int nl = tid >> 3, k0 = 8 + ((tid & 7) << 2);
#pragma unroll
      for (int q = 0; q < 4; ++q) sX[nl * 40 + k0 + q] = (_Float16)0.f; }
    if (do_gate) {
        int nl = tid >> 3, f = tid & 7, n = nb + nl;
        sX[nl * 40 + f] = (n < N) ? (_Float16)aggXt[((size_t)tn * N + n) * 8 + f] : (_Float16)0.f;
    }
    // Aglobh -> sA cols 0..63 (u32 packed)
    for (int i = tid; i < 2048; i += 512) {
        int nl = i >> 5, c2 = i & 31, n = nb + nl;
        ((unsigned*)sA)[nl * 68 + c2] = (n < N) ? Aglobh32[(size_t)n * 32 + c2] : 0u;
    }
    // gather gconv(RH1) -> sA cols 64..127
    for (int i = 0; i < 4; ++i) {
        int pr = wid * 4 + i;
        int nlA = pr * 2, nlB = nlA + 1;
        int nA = nb + nlA, nB = nb + nlB;
        int begA = 0, degA = 0, begB = 0, degB = 0;
        if (nA < N) { begA = rowptr[nA]; degA = rowptr[nA + 1] - begA; }
        if (nB < N) { begB = rowptr[nB]; degB = rowptr[nB + 1] - begB; }
        float o0, o1;
        gpair16((const unsigned*)RH1h, csr_ew, begA, degA, begB, degB, lane, o0, o1);
        int nl = (lane < 32) ? nlA : nlB;
        int c2 = lane & 31;
        sA[nl * 136 + 64 + 2 * c2] = (_Float16)o0;
        sA[nl * 136 + 64 + 2 * c2 + 1] = (_Float16)o1;
    }
    __syncthreads();
    const int ln15 = lane & 15, quad = lane >> 4;
    const int mt = wid & 3, ng = wid >> 2;
    const int mrow = mt * 16 + ln15;
    f16x8 afr[4];
#pragma unroll
    for (int kc = 0; kc < 4; ++kc)
        afr[kc] = *(const f16x8*)&sA[mrow * 136 + kc * 32 + quad * 8];
    // cand: c1[64][64] = sA @ Wc1t^T (K=128), 2 N-tiles/wave
    f32x4 accc[2];
    int colc[2];
#pragma unroll
    for (int nt = 0; nt < 2; ++nt) {
        int col = (ng * 2 + nt) * 16 + ln15;
        colc[nt] = col;
        float b = bc1[col];
        f32x4 a = {b, b, b, b};
#pragma unroll
        for (int kc = 0; kc < 4; ++kc) {
            f16x8 bfr = *(const f16x8*)&Wc1t[(size_t)col * 128 + kc * 32 + quad * 8];
            a = __builtin_amdgcn_mfma_f32_16x16x32_f16(afr[kc], bfr, a, 0, 0, 0);
        }
        accc[nt] = a;
    }
    // gate0(t+1): rz0[64][128] = sX@Wg0t_x + sA(0:64)@Wg0t_h, 4 N-tiles/wave
    f32x4 accg[4];
    int colg[4];
    if (do_gate) {
        f16x8 xfr = *(const f16x8*)&sX[mrow * 40 + quad * 8];
#pragma unroll
        for (int nt = 0; nt < 4; ++nt) {
            int col = (ng * 4 + nt) * 16 + ln15;
            colg[nt] = col;
            float b = bg0[col];
            f32x4 a = {b, b, b, b};
            f16x8 bx = *(const f16x8*)&Wg0t_x[(size_t)col * 32 + quad * 8];
            a = __builtin_amdgcn_mfma_f32_16x16x32_f16(xfr, bx, a, 0, 0, 0);
#pragma unroll
            for (int kc = 0; kc < 2; ++kc) {
                f16x8 bfr = *(const f16x8*)&Wg0t_h[(size_t)col * 64 + kc * 32 + quad * 8];
                a = __builtin_amdgcn_mfma_f32_16x16x32_f16(afr[kc], bfr, a, 0, 0, 0);
            }
            accg[nt] = a;
        }
    }
    __syncthreads();
    // stage: c1 -> sA cols 64..127; r0 -> sA cols 0..63 (z0 stays in regs)
#pragma unroll
    for (int nt = 0; nt < 2; ++nt) {
#pragma unroll
        for (int r = 0; r < 4; ++r) {
            float e = __expf(2.f * accc[nt][r]);
            float c = 1.f - 2.f / (e + 1.f);
            int row = mt * 16 + quad * 4 + r;
            sA[row * 136 + 64 + colc[nt]] = (_Float16)c;
        }
    }
    if (do_gate) {
#pragma unroll
        for (int nt = 0; nt < 4; ++nt) {
            if (colg[nt] < 64) {
#pragma unroll
                for (int r = 0; r < 4; ++r) {
                    float s = 1.f / (1.f + __expf(-accg[nt][r]));
                    int row = mt * 16 + quad * 4 + r;
                    sA[row * 136 + colg[nt]] = (_Float16)s;
                }
            }
        }
    }
    __syncthreads();
    // epilogue-1: h1 update (+RH0h, +final out)
    for (int i = tid; i < 4096; i += 512) {
        int nl = i >> 6, cc = i & 63, n = nb + nl;
        float nh = 0.f;
        if (n < N) {
            size_t idx = (size_t)n * 64 + cc;
            float z1 = (float)Zh[idx];
            float hv = h1f[idx];
            nh = z1 * hv + (1.f - z1) * (float)sA[nl * 136 + 64 + cc];
            if (!final) {
                h1f[idx] = nh;
                reinterpret_cast<__half*>(h01)[idx * 2 + 1] = __float2half(nh);
            }
            if (do_gate) RH0h[idx] = (_Float16)((float)sA[nl * 136 + cc] * h0f[idx]);
        }
        if (final) {
            float p = nh * Wout[cc];
            for (int off = 32; off > 0; off >>= 1) p += __shfl_down(p, off);
            if (cc == 0 && n < N) out[n] = p + bout[0];
        }
    }
    if (do_gate) {
        __syncthreads();
        // stage z0 (gate cols >= 64) -> sA cols 0..63
#pragma unroll
        for (int nt = 0; nt < 4; ++nt) {
            if (colg[nt] >= 64) {
#pragma unroll
                for (int r = 0; r < 4; ++r) {
                    float s = 1.f / (1.f + __expf(-accg[nt][r]));
                    int row = mt * 16 + quad * 4 + r;
                    sA[row * 136 + (colg[nt] - 64)] = (_Float16)s;
                }
            }
        }
        __syncthreads();
        for (int i = tid; i < 4096; i += 512) {
            int nl = i >> 6, cc = i & 63, n = nb + nl;
            if (n < N) Zh[(size_t)n * 64 + cc] = sA[nl * 136 + cc];
        }
    }
}

static inline size_t align16(size_t v) { return (v + 15) & ~(size_t)15; }

extern "C" void kernel_launch(void* const* d_in, const int* in_sizes, int n_in,
                              void* d_out, int out_size, void* d_ws, size_t ws_size,
                              hipStream_t stream) {
    const float* x   = (const float*)d_in[0];
    const int*   ei  = (const int*)d_in[1];
    const float* ew  = (const float*)d_in[2];
    const float* Wg0 = (const float*)d_in[3];
    const float* bg0 = (const float*)d_in[4];
    const float* Wc0 = (const float*)d_in[5];
    const float* bc0 = (const float*)d_in[6];
    const float* Wg1 = (const float*)d_in[7];
    const float* bg1 = (const float*)d_in[8];
    const float* Wc1 = (const float*)d_in[9];
    const float* bc1 = (const float*)d_in[10];
    const float* Wout = (const float*)d_in[11];
    const float* bout = (const float*)d_in[12];

    const int N = in_sizes[0] / FT;
    const int E = in_sizes[2];
    const int* src = ei;
    const int* dst = ei + E;

    char* base = (char*)d_ws;
    size_t off = 0;
    int* deg = (int*)(base + off);            off = align16(off + (size_t)N * 4);
    int* cursor = (int*)(base + off);         off = align16(off + (size_t)N * 4);
    int* rowptr = (int*)(base + off);         off = align16(off + (size_t)(N + 1) * 4);
    int* part = (int*)(base + off);           off = align16(off + 256 * 4);
    unsigned* csr_ew = (unsigned*)(base + off);  off = align16(off + (size_t)E * 4);
    float* aggXt = (float*)(base + off);      off = align16(off + (size_t)N * FT * 4);
    float* h0f = (float*)(base + off);        off = align16(off + (size_t)N * 64 * 4);
    float* h1f = (float*)(base + off);        off = align16(off + (size_t)N * 64 * 4);
    unsigned* h01 = (unsigned*)(base + off);  off = align16(off + (size_t)N * 64 * 4);
    unsigned* Aglobh32 = (unsigned*)(base + off); off = align16(off + (size_t)N * 32 * 4);
    _Float16* Zh = (_Float16*)(base + off);   off = align16(off + (size_t)N * 64 * 2);
    _Float16* RH0h = (_Float16*)(base + off); off = align16(off + (size_t)N * 64 * 2);
    _Float16* RH1h = (_Float16*)(base + off); off = align16(off + (size_t)N * 64 * 2);
    _Float16* xh = (_Float16*)(base + off);   off = align16(off + (size_t)N * FT * 2);
    _Float16* Wg1t = (_Float16*)(base + off); off = align16(off + 128 * 128 * 2);
    _Float16* Wc1t = (_Float16*)(base + off); off = align16(off + 64 * 128 * 2);
    _Float16* Wc0t = (_Float16*)(base + off); off = align16(off + 64 * 96 * 2);
    _Float16* Wg0t_h = (_Float16*)(base + off); off = align16(off + 128 * 64 * 2);
    _Float16* Wg0t_x = (_Float16*)(base + off); off = align16(off + 128 * 32 * 2);

    const int gE   = (E + 255) / 256;
    const int gN4  = (N + 3) / 4;
    const int gN64 = (N + 63) / 64;
    const int G    = (N + 255) / 256;

    hipMemsetAsync(deg, 0, (size_t)N * 4, stream);
    hipMemsetAsync(h0f, 0, (size_t)N * 64 * 4, stream);
    hipMemsetAsync(h1f, 0, (size_t)N * 64 * 4, stream);
    hipMemsetAsync(h01, 0, (size_t)N * 64 * 4, stream);
    hipMemsetAsync(RH0h, 0, (size_t)N * 64 * 2, stream);

    x2h_k<<<(N * FT + 255) / 256, 256, 0, stream>>>(x, xh, N * FT);
    wprep_k<<<64, 256, 0, stream>>>(Wg0, Wc0, Wg1, Wc1, Wg1t, Wc1t, Wc0t, Wg0t_h, Wg0t_x);
    hist_k<<<gE, 256, 0, stream>>>(dst, deg, E);
    partial_k<<<G, 256, 0, stream>>>(deg, part, N);
    scanpart_k<<<1, 256, 0, stream>>>(part, rowptr, G, N);
    scanchunk_k<<<G, 256, 0, stream>>>(deg, part, rowptr, cursor, N);
    fill_k<<<gE, 256, 0, stream>>>(src, dst, ew, cursor, csr_ew, E);
    gather96_k<<<gN4, 256, 0, stream>>>(xh, rowptr, csr_ew, aggXt, N);

    // t=0: h0=0 -> RH0h=0 (memset); z0 from aggX only
    g0z_k<<<(N * 64 + 255) / 256, 256, 0, stream>>>(aggXt, Wg0, bg0, Zh, N);

    for (int t = 0; t < TSTEPS; ++t) {
        l0_cand<<<gN64, 512, 0, stream>>>(RH0h, aggXt, t, rowptr, csr_ew,
                                          Wc0t, bc0, Zh, h0f, h01, N);
        l1_gate<<<gN64, 512, 0, stream>>>(h01, h1f, rowptr, csr_ew,
                                          Wg1t, bg1, Aglobh32, Zh, RH1h, N);
        l1_cand_fused<<<gN64, 512, 0, stream>>>(RH1h, Aglobh32, aggXt, t + 1,
                                                (t + 1 < TSTEPS) ? 1 : 0,
                                                (t + 1 == TSTEPS) ? 1 : 0,
                                                rowptr, csr_ew,
                                                Wc1t, bc1, Wg0t_h, Wg0t_x, bg0,
                                                h0f, Zh, RH0h, h1f, h01,
                                                Wout, bout, (float*)d_out, N);
    }
}